// Round 1
// baseline (873.537 us; speedup 1.0000x reference)
//
#include <hip/hip_runtime.h>

// ---------------------------------------------------------------------------
// Transformer block fwd (B=4,T=2048,C=1024,H=16,HS=64,FF=4096), fp32 in/out,
// bf16 MFMA internally.  Softmax is over the QUERY axis (axis=-2): two-pass
// column-softmax (pass A: per-column m,l stats; pass B: normalized PV).
// ---------------------------------------------------------------------------

#define T_SEQ 2048
#define NBATCH 4

typedef __attribute__((ext_vector_type(8))) short short8;  // 8 x bf16 (4 VGPR)
typedef __attribute__((ext_vector_type(4))) float f32x4;   // MFMA 16x16 acc

typedef __attribute__((address_space(1))) unsigned int g_u32;
typedef __attribute__((address_space(3))) unsigned int l_u32;

__device__ __forceinline__ unsigned short f2bf(float f) {
  union { float f; unsigned u; } x; x.f = f;
  unsigned r = (x.u + 0x7FFFu + ((x.u >> 16) & 1u)) >> 16;  // RNE
  return (unsigned short)r;
}

__device__ __forceinline__ void g2lds16(const void* g, void* l) {
  // async global->LDS, 16B/lane; LDS dest is wave-uniform base + lane*16
  __builtin_amdgcn_global_load_lds((g_u32*)g, (l_u32*)l, 16, 0, 0);
}

// ---------------------------------------------------------------------------
// Generic bf16 GEMM: C[M,N] = A[M,K] @ Bt[N,K]^T   (Bt is B transposed)
// EPI 0: out bf16 = acc            (QKV)
// EPI 1: out f32  = acc + bias[n] + resid[m,n]   (Wo-resid, FFN2-resid)
// EPI 2: out bf16 = relu(acc + bias[n])          (FFN1)
// 128x128 tile, BK=64, 4 waves (2x2), 4x4 16x16x32 frags/wave.
// LDS XOR-swizzle (granule col ^= row&7) applied on the GLOBAL source side of
// global_load_lds (LDS dest stays linear) and on the ds_read side.
// ---------------------------------------------------------------------------
template <int EPI>
__global__ __launch_bounds__(256) void gemm_bt(
    const unsigned short* __restrict__ A, const unsigned short* __restrict__ Bt,
    int M, int N, int K,
    unsigned short* __restrict__ out16, float* __restrict__ outF,
    const float* __restrict__ bias, const float* __restrict__ resid) {
  __shared__ unsigned short ldsA[128 * 64];
  __shared__ unsigned short ldsB[128 * 64];
  const int tid = threadIdx.x;
  const int lane = tid & 63, wid = tid >> 6;
  const int wm = wid >> 1, wn = wid & 1;
  const int mBase = blockIdx.y * 128, nBase = blockIdx.x * 128;

  f32x4 acc[4][4];
#pragma unroll
  for (int i = 0; i < 4; ++i)
#pragma unroll
    for (int j = 0; j < 4; ++j)
#pragma unroll
      for (int e = 0; e < 4; ++e) acc[i][j][e] = 0.f;

  const int nKT = K >> 6;
  for (int kt = 0; kt < nKT; ++kt) {
    const int k0 = kt << 6;
#pragma unroll
    for (int it = 0; it < 4; ++it) {
      int g = it * 256 + wid * 64 + lane;     // granule id 0..1023 (16B each)
      int row = g >> 3, colL = g & 7;
      int col = colL ^ (row & 7);             // inverse-swizzled source
      g2lds16(A + ((size_t)(mBase + row) * K + k0 + col * 8),
              &ldsA[(it * 256 + wid * 64) * 8]);
      g2lds16(Bt + ((size_t)(nBase + row) * K + k0 + col * 8),
              &ldsB[(it * 256 + wid * 64) * 8]);
    }
    __syncthreads();  // drains vmcnt -> tiles visible

    short8 af[4][2], bf[4][2];
#pragma unroll
    for (int fm = 0; fm < 4; ++fm)
#pragma unroll
      for (int ks = 0; ks < 2; ++ks) {
        int r = wm * 64 + fm * 16 + (lane & 15);
        int c = (ks * 4 + (lane >> 4)) ^ (r & 7);  // swizzled read
        af[fm][ks] = *(const short8*)&ldsA[r * 64 + c * 8];
      }
#pragma unroll
    for (int fn = 0; fn < 4; ++fn)
#pragma unroll
      for (int ks = 0; ks < 2; ++ks) {
        int r = wn * 64 + fn * 16 + (lane & 15);
        int c = (ks * 4 + (lane >> 4)) ^ (r & 7);
        bf[fn][ks] = *(const short8*)&ldsB[r * 64 + c * 8];
      }
#pragma unroll
    for (int fm = 0; fm < 4; ++fm)
#pragma unroll
      for (int fn = 0; fn < 4; ++fn)
#pragma unroll
        for (int ks = 0; ks < 2; ++ks)
          acc[fm][fn] = __builtin_amdgcn_mfma_f32_16x16x32_bf16(
              af[fm][ks], bf[fn][ks], acc[fm][fn], 0, 0, 0);
    __syncthreads();  // before next stage overwrites LDS
  }

#pragma unroll
  for (int fm = 0; fm < 4; ++fm)
#pragma unroll
    for (int fn = 0; fn < 4; ++fn) {
      int col = nBase + wn * 64 + fn * 16 + (lane & 15);
      int row0 = mBase + wm * 64 + fm * 16 + ((lane >> 4) << 2);
      if (EPI == 0) {
#pragma unroll
        for (int r = 0; r < 4; ++r)
          out16[(size_t)(row0 + r) * N + col] = f2bf(acc[fm][fn][r]);
      } else if (EPI == 1) {
        float bv = bias[col];
#pragma unroll
        for (int r = 0; r < 4; ++r) {
          size_t idx = (size_t)(row0 + r) * N + col;
          outF[idx] = acc[fm][fn][r] + bv + resid[idx];
        }
      } else {
        float bv = bias[col];
#pragma unroll
        for (int r = 0; r < 4; ++r)
          out16[(size_t)(row0 + r) * N + col] =
              f2bf(fmaxf(acc[fm][fn][r] + bv, 0.f));
      }
    }
}

// ---------------------------------------------------------------------------
// LayerNorm + bf16 cast.  One block per row of 1024.
// ---------------------------------------------------------------------------
__global__ __launch_bounds__(256) void ln_bf16(
    const float* __restrict__ x, const float* __restrict__ gw,
    const float* __restrict__ bw, unsigned short* __restrict__ out) {
  __shared__ float red[8];
  const int row = blockIdx.x, tid = threadIdx.x;
  const float4 v = ((const float4*)(x + (size_t)row * 1024))[tid];
  float s = v.x + v.y + v.z + v.w;
  float q = v.x * v.x + v.y * v.y + v.z * v.z + v.w * v.w;
#pragma unroll
  for (int off = 32; off >= 1; off >>= 1) {
    s += __shfl_down(s, off);
    q += __shfl_down(q, off);
  }
  const int lane = tid & 63, wid = tid >> 6;
  if (lane == 0) { red[wid] = s; red[4 + wid] = q; }
  __syncthreads();
  float S = red[0] + red[1] + red[2] + red[3];
  float Q = red[4] + red[5] + red[6] + red[7];
  float mu = S * (1.f / 1024.f);
  float var = Q * (1.f / 1024.f) - mu * mu;
  float rs = rsqrtf(var + 1e-5f);
  int c = tid * 4;
  ushort4 ov;
  ov.x = f2bf((v.x - mu) * rs * gw[c + 0] + bw[c + 0]);
  ov.y = f2bf((v.y - mu) * rs * gw[c + 1] + bw[c + 1]);
  ov.z = f2bf((v.z - mu) * rs * gw[c + 2] + bw[c + 2]);
  ov.w = f2bf((v.w - mu) * rs * gw[c + 3] + bw[c + 3]);
  *(ushort4*)&out[(size_t)row * 1024 + c] = ov;
}

// ---------------------------------------------------------------------------
// Weight packing: per-head Wq/Wk/Wv [H,C,HS] f32 -> Wqkv bf16 [3072][1024]
// row n = proj*1024 + h*64 + d, col = c  (B^T layout for the GEMM).
// ---------------------------------------------------------------------------
__global__ __launch_bounds__(256) void pack_qkv(
    const float* __restrict__ Wq, const float* __restrict__ Wk,
    const float* __restrict__ Wv, unsigned short* __restrict__ out) {
  __shared__ float tile[64 * 65];
  const int tid = threadIdx.x;
  const float* W = (blockIdx.z == 0) ? Wq : (blockIdx.z == 1) ? Wk : Wv;
  const int h = blockIdx.y, r0 = blockIdx.x * 64;
#pragma unroll
  for (int it = 0; it < 4; ++it) {
    int e4 = it * 256 + tid;
    int r = e4 >> 4, c4 = e4 & 15;
    float4 v = *(const float4*)&W[((size_t)h * 1024 + r0 + r) * 64 + c4 * 4];
    tile[r * 65 + c4 * 4 + 0] = v.x;
    tile[r * 65 + c4 * 4 + 1] = v.y;
    tile[r * 65 + c4 * 4 + 2] = v.z;
    tile[r * 65 + c4 * 4 + 3] = v.w;
  }
  __syncthreads();
#pragma unroll
  for (int it = 0; it < 4; ++it) {
    int e4 = it * 256 + tid;
    int d = e4 >> 4, r4 = e4 & 15;
    ushort4 ov;
    ov.x = f2bf(tile[(r4 * 4 + 0) * 65 + d]);
    ov.y = f2bf(tile[(r4 * 4 + 1) * 65 + d]);
    ov.z = f2bf(tile[(r4 * 4 + 2) * 65 + d]);
    ov.w = f2bf(tile[(r4 * 4 + 3) * 65 + d]);
    *(ushort4*)&out[(size_t)(blockIdx.z * 1024 + h * 64 + d) * 1024 + r0 +
                    r4 * 4] = ov;
  }
}

// Generic transpose+cast: in f32 [R,C] -> out bf16 [C,R].  grid (R/64, C/64).
__global__ __launch_bounds__(256) void transpose_cast(
    const float* __restrict__ in, unsigned short* __restrict__ out, int R,
    int C) {
  __shared__ float tile[64 * 65];
  const int tid = threadIdx.x;
  const int r0 = blockIdx.x * 64, c0 = blockIdx.y * 64;
#pragma unroll
  for (int it = 0; it < 4; ++it) {
    int e4 = it * 256 + tid;
    int r = e4 >> 4, c4 = e4 & 15;
    float4 v = *(const float4*)&in[(size_t)(r0 + r) * C + c0 + c4 * 4];
    tile[r * 65 + c4 * 4 + 0] = v.x;
    tile[r * 65 + c4 * 4 + 1] = v.y;
    tile[r * 65 + c4 * 4 + 2] = v.z;
    tile[r * 65 + c4 * 4 + 3] = v.w;
  }
  __syncthreads();
#pragma unroll
  for (int it = 0; it < 4; ++it) {
    int e4 = it * 256 + tid;
    int c = e4 >> 4, r4 = e4 & 15;
    ushort4 ov;
    ov.x = f2bf(tile[(r4 * 4 + 0) * 65 + c]);
    ov.y = f2bf(tile[(r4 * 4 + 1) * 65 + c]);
    ov.z = f2bf(tile[(r4 * 4 + 2) * 65 + c]);
    ov.w = f2bf(tile[(r4 * 4 + 3) * 65 + c]);
    *(ushort4*)&out[(size_t)(c0 + c) * R + r0 + r4 * 4] = ov;
  }
}

// V slice of qkv [B,T,3072] (cols 2048..3071) -> vT bf16 [B*H*64][T]
__global__ __launch_bounds__(256) void vtrans(
    const unsigned short* __restrict__ qkv, unsigned short* __restrict__ vT) {
  __shared__ unsigned short tile[64 * 66];
  const int tid = threadIdx.x;
  const int bh = blockIdx.y, b = bh >> 4, h = bh & 15;
  const int t0 = blockIdx.x * 64;
#pragma unroll
  for (int it = 0; it < 8; ++it) {
    int e2 = it * 256 + tid;
    int r = e2 >> 5, c2 = e2 & 31;
    unsigned v = *(const unsigned*)&qkv[(size_t)(b * T_SEQ + t0 + r) * 3072 +
                                        2048 + h * 64 + c2 * 2];
    *(unsigned*)&tile[r * 66 + c2 * 2] = v;
  }
  __syncthreads();
#pragma unroll
  for (int it = 0; it < 8; ++it) {
    int e2 = it * 256 + tid;
    int d = e2 >> 5, t2 = e2 & 31;
    unsigned short a = tile[(t2 * 2) * 66 + d];
    unsigned short bb = tile[(t2 * 2 + 1) * 66 + d];
    unsigned pk = (unsigned)a | ((unsigned)bb << 16);
    *(unsigned*)&vT[(size_t)(bh * 64 + d) * T_SEQ + t0 + t2 * 2] = pk;
  }
}

// ---------------------------------------------------------------------------
// Attention pass A: per-column softmax stats over the QUERY axis.
// One wave per (bh, 64-col s-tile); streams 16-row t-tiles from t=s0..T.
// Scores via mfma(Q, K^T) directly from global (bf16x8 frags).
// ---------------------------------------------------------------------------
__global__ __launch_bounds__(64) void attn_stats(
    const unsigned short* __restrict__ qkv, float* __restrict__ mOut,
    float* __restrict__ linvOut) {
  const int lane = threadIdx.x;
  const int bh = blockIdx.y, b = bh >> 4, h = bh & 15;
  const int s0 = blockIdx.x * 64;
  short8 kf[4][2];
#pragma unroll
  for (int fn = 0; fn < 4; ++fn)
#pragma unroll
    for (int ks = 0; ks < 2; ++ks) {
      int s = s0 + fn * 16 + (lane & 15);
      kf[fn][ks] = *(const short8*)&qkv[(size_t)(b * T_SEQ + s) * 3072 + 1024 +
                                        h * 64 + ks * 32 + ((lane >> 4) << 3)];
    }
  float mcol[4], lcol[4];
#pragma unroll
  for (int fn = 0; fn < 4; ++fn) {
    mcol[fn] = -__builtin_inff();
    lcol[fn] = 0.f;
  }
  for (int t0 = s0; t0 < T_SEQ; t0 += 16) {
    short8 qf[2];
#pragma unroll
    for (int ks = 0; ks < 2; ++ks) {
      int t = t0 + (lane & 15);
      qf[ks] = *(const short8*)&qkv[(size_t)(b * T_SEQ + t) * 3072 + h * 64 +
                                    ks * 32 + ((lane >> 4) << 3)];
    }
    f32x4 sc[4];
#pragma unroll
    for (int fn = 0; fn < 4; ++fn)
#pragma unroll
      for (int e = 0; e < 4; ++e) sc[fn][e] = 0.f;
#pragma unroll
    for (int fn = 0; fn < 4; ++fn)
#pragma unroll
      for (int ks = 0; ks < 2; ++ks)
        sc[fn] = __builtin_amdgcn_mfma_f32_16x16x32_bf16(qf[ks], kf[fn][ks],
                                                         sc[fn], 0, 0, 0);
    const int tRow = t0 + ((lane >> 4) << 2);
#pragma unroll
    for (int fn = 0; fn < 4; ++fn) {
      int s = s0 + fn * 16 + (lane & 15);
      float w[4];
#pragma unroll
      for (int r = 0; r < 4; ++r) {
        float ws = sc[fn][r] * 0.125f;
        w[r] = (tRow + r >= s) ? ws : -__builtin_inff();
      }
      float tmax = fmaxf(fmaxf(w[0], w[1]), fmaxf(w[2], w[3]));
      float mn = fmaxf(mcol[fn], tmax);
      if (mn != -__builtin_inff()) {
        float lsum = __expf(w[0] - mn) + __expf(w[1] - mn) +
                     __expf(w[2] - mn) + __expf(w[3] - mn);
        lcol[fn] = lcol[fn] * __expf(mcol[fn] - mn) + lsum;
        mcol[fn] = mn;
      }
    }
  }
  // combine the 4 lane-groups (same column lives in lanes l, l+16, l+32, l+48)
#pragma unroll
  for (int fn = 0; fn < 4; ++fn) {
#pragma unroll
    for (int off = 32; off >= 16; off >>= 1) {
      float mo = __shfl_down(mcol[fn], off);
      float lo = __shfl_down(lcol[fn], off);
      float mn = fmaxf(mcol[fn], mo);
      if (mn != -__builtin_inff()) {
        lcol[fn] = lcol[fn] * __expf(mcol[fn] - mn) + lo * __expf(mo - mn);
        mcol[fn] = mn;
      }
    }
  }
  if (lane < 16) {
#pragma unroll
    for (int fn = 0; fn < 4; ++fn) {
      int s = s0 + fn * 16 + lane;
      mOut[(size_t)bh * T_SEQ + s] = mcol[fn];
      linvOut[(size_t)bh * T_SEQ + s] = 1.f / lcol[fn];
    }
  }
}

// ---------------------------------------------------------------------------
// Attention pass B: O[t,:] = sum_s exp(S[t,s]-m[s])*linv[s] * V[s,:]
// Block = 128 q-rows (4 waves x 32 rows), s-tiles of 64.  P goes through a
// XOR-swizzled LDS tile (row-major [128][64] bf16, byte ^= (row&7)<<4).
// ---------------------------------------------------------------------------
__global__ __launch_bounds__(256) void attn_pv(
    const unsigned short* __restrict__ qkv, const unsigned short* __restrict__ vT,
    const float* __restrict__ mIn, const float* __restrict__ linvIn,
    unsigned short* __restrict__ o) {
  __shared__ unsigned short pl[128 * 64];
  const int tid = threadIdx.x, lane = tid & 63, wid = tid >> 6;
  const int bh = blockIdx.y, b = bh >> 4, h = bh & 15;
  const int t0 = blockIdx.x * 128;
  short8 qf[2][2];
#pragma unroll
  for (int mf = 0; mf < 2; ++mf)
#pragma unroll
    for (int ks = 0; ks < 2; ++ks) {
      int t = t0 + wid * 32 + mf * 16 + (lane & 15);
      qf[mf][ks] = *(const short8*)&qkv[(size_t)(b * T_SEQ + t) * 3072 + h * 64 +
                                        ks * 32 + ((lane >> 4) << 3)];
    }
  f32x4 oacc[2][4];
#pragma unroll
  for (int i = 0; i < 2; ++i)
#pragma unroll
    for (int j = 0; j < 4; ++j)
#pragma unroll
      for (int e = 0; e < 4; ++e) oacc[i][j][e] = 0.f;

  const int nST = (t0 >> 6) + 2;
  for (int st = 0; st < nST; ++st) {
    const int s0 = st * 64;
    f32x4 sc[2][4];
#pragma unroll
    for (int i = 0; i < 2; ++i)
#pragma unroll
      for (int j = 0; j < 4; ++j)
#pragma unroll
        for (int e = 0; e < 4; ++e) sc[i][j][e] = 0.f;
#pragma unroll
    for (int fn = 0; fn < 4; ++fn)
#pragma unroll
      for (int ks = 0; ks < 2; ++ks) {
        short8 kfr =
            *(const short8*)&qkv[(size_t)(b * T_SEQ + s0 + fn * 16 +
                                          (lane & 15)) * 3072 + 1024 + h * 64 +
                                 ks * 32 + ((lane >> 4) << 3)];
        sc[0][fn] = __builtin_amdgcn_mfma_f32_16x16x32_bf16(qf[0][ks], kfr,
                                                            sc[0][fn], 0, 0, 0);
        sc[1][fn] = __builtin_amdgcn_mfma_f32_16x16x32_bf16(qf[1][ks], kfr,
                                                            sc[1][fn], 0, 0, 0);
      }
    // normalize -> bf16 P into swizzled LDS
#pragma unroll
    for (int mf = 0; mf < 2; ++mf)
#pragma unroll
      for (int fn = 0; fn < 4; ++fn) {
        int sg = s0 + fn * 16 + (lane & 15);
        float mc = mIn[(size_t)bh * T_SEQ + sg];
        float li = linvIn[(size_t)bh * T_SEQ + sg];
        int rowB = wid * 32 + mf * 16 + ((lane >> 4) << 2);
        int colB = fn * 16 + (lane & 15);
#pragma unroll
        for (int r = 0; r < 4; ++r) {
          int t = t0 + rowB + r;
          float p =
              (t >= sg) ? __expf(sc[mf][fn][r] * 0.125f - mc) * li : 0.f;
          int byteoff =
              (rowB + r) * 128 + ((colB * 2) ^ (((rowB + r) & 7) << 4));
          *(unsigned short*)((char*)pl + byteoff) = f2bf(p);
        }
      }
    __syncthreads();
    // PV: A = P (LDS, swizzled read), B^T = vT rows (global, k-contiguous)
#pragma unroll
    for (int ks = 0; ks < 2; ++ks) {
      short8 pa[2];
#pragma unroll
      for (int mf = 0; mf < 2; ++mf) {
        int row = wid * 32 + mf * 16 + (lane & 15);
        int bo = row * 128 +
                 ((ks * 64 + ((lane >> 4) << 4)) ^ ((row & 7) << 4));
        pa[mf] = *(const short8*)((const char*)pl + bo);
      }
#pragma unroll
      for (int df = 0; df < 4; ++df) {
        short8 vb = *(const short8*)&vT[(size_t)(bh * 64 + df * 16 +
                                                 (lane & 15)) * T_SEQ + s0 +
                                        ks * 32 + ((lane >> 4) << 3)];
        oacc[0][df] = __builtin_amdgcn_mfma_f32_16x16x32_bf16(pa[0], vb,
                                                              oacc[0][df], 0, 0, 0);
        oacc[1][df] = __builtin_amdgcn_mfma_f32_16x16x32_bf16(pa[1], vb,
                                                              oacc[1][df], 0, 0, 0);
      }
    }
    __syncthreads();
  }
  // write O as bf16 [B,T,C] (c = h*64+d)
#pragma unroll
  for (int mf = 0; mf < 2; ++mf)
#pragma unroll
    for (int df = 0; df < 4; ++df) {
      int d = df * 16 + (lane & 15);
      int row0 = t0 + wid * 32 + mf * 16 + ((lane >> 4) << 2);
#pragma unroll
      for (int r = 0; r < 4; ++r)
        o[(size_t)(b * T_SEQ + row0 + r) * 1024 + h * 64 + d] =
            f2bf(oacc[mf][df][r]);
    }
}

// ---------------------------------------------------------------------------
extern "C" void kernel_launch(void* const* d_in, const int* in_sizes, int n_in,
                              void* d_out, int out_size, void* d_ws,
                              size_t ws_size, hipStream_t stream) {
  const float* x = (const float*)d_in[0];
  const float* Wq = (const float*)d_in[1];
  const float* Wk = (const float*)d_in[2];
  const float* Wv = (const float*)d_in[3];
  const float* Wo = (const float*)d_in[4];
  const float* bo = (const float*)d_in[5];
  const float* g1 = (const float*)d_in[6];
  const float* b1 = (const float*)d_in[7];
  const float* g2 = (const float*)d_in[8];
  const float* b2 = (const float*)d_in[9];
  const float* W1 = (const float*)d_in[10];
  const float* bf1 = (const float*)d_in[11];
  const float* W2 = (const float*)d_in[12];
  const float* bf2 = (const float*)d_in[13];
  float* out = (float*)d_out;

  char* ws = (char*)d_ws;
  size_t off = 0;
  auto alloc = [&](size_t bytes) {
    char* p = ws + off;
    off += (bytes + 255) & ~(size_t)255;
    return p;
  };
  unsigned short* Wqkv = (unsigned short*)alloc(3072ull * 1024 * 2);
  unsigned short* WoT = (unsigned short*)alloc(1024ull * 1024 * 2);
  unsigned short* W1T = (unsigned short*)alloc(4096ull * 1024 * 2);
  unsigned short* W2T = (unsigned short*)alloc(1024ull * 4096 * 2);
  unsigned short* hbuf = (unsigned short*)alloc(8192ull * 1024 * 2);  // h, then o
  char* regionE = alloc(8192ull * 3072 * 2 + 64ull * 64 * 2048 * 2);
  unsigned short* qkv = (unsigned short*)regionE;           // live: QKV..attn
  unsigned short* vT = (unsigned short*)(regionE + 8192ull * 3072 * 2);
  unsigned short* act = (unsigned short*)regionE;           // live: FFN (after attn)
  float* mbuf = (float*)alloc(64ull * 2048 * 4);
  float* lbuf = (float*)alloc(64ull * 2048 * 4);
  float* x1 = (float*)alloc(8192ull * 1024 * 4);
  unsigned short* fbuf = (unsigned short*)alloc(8192ull * 1024 * 2);
  unsigned short* obuf = hbuf;  // h dead after QKV GEMM

  (void)in_sizes; (void)n_in; (void)out_size; (void)ws_size;

  // weight packing (B^T bf16 layouts)
  pack_qkv<<<dim3(16, 16, 3), 256, 0, stream>>>(Wq, Wk, Wv, Wqkv);
  transpose_cast<<<dim3(16, 16), 256, 0, stream>>>(Wo, WoT, 1024, 1024);
  transpose_cast<<<dim3(16, 64), 256, 0, stream>>>(W1, W1T, 1024, 4096);
  transpose_cast<<<dim3(64, 16), 256, 0, stream>>>(W2, W2T, 4096, 1024);
  // LN1 -> h
  ln_bf16<<<8192, 256, 0, stream>>>(x, g1, b1, hbuf);
  // QKV projection: [8192,1024]@[1024,3072]
  gemm_bt<0><<<dim3(24, 64), 256, 0, stream>>>(hbuf, Wqkv, 8192, 3072, 1024,
                                               qkv, nullptr, nullptr, nullptr);
  // V transpose for PV B-operand
  vtrans<<<dim3(32, 64), 256, 0, stream>>>(qkv, vT);
  // attention
  attn_stats<<<dim3(32, 64), 64, 0, stream>>>(qkv, mbuf, lbuf);
  attn_pv<<<dim3(16, 64), 256, 0, stream>>>(qkv, vT, mbuf, lbuf, obuf);
  // x1 = x + O@Wo + bo
  gemm_bt<1><<<dim3(8, 64), 256, 0, stream>>>(obuf, WoT, 8192, 1024, 1024,
                                              nullptr, x1, bo, x);
  // LN2 -> f
  ln_bf16<<<8192, 256, 0, stream>>>(x1, g2, b2, fbuf);
  // FFN1: relu(f@W1 + bf1) -> act bf16 [8192,4096]
  gemm_bt<2><<<dim3(32, 64), 256, 0, stream>>>(fbuf, W1T, 8192, 4096, 1024, act,
                                               nullptr, bf1, nullptr);
  // FFN2 + residual: out = x1 + act@W2 + bf2
  gemm_bt<1><<<dim3(8, 64), 256, 0, stream>>>(act, W2T, 8192, 1024, 4096,
                                              nullptr, out, bf2, x1);
}

// Round 2
// 615.295 us; speedup vs baseline: 1.4197x; 1.4197x over previous
//
#include <hip/hip_runtime.h>

// ---------------------------------------------------------------------------
// Transformer block fwd (B=4,T=2048,C=1024,H=16,HS=64,FF=4096), fp32 in/out,
// bf16 MFMA internally.  Softmax is over the QUERY axis (axis=-2): two-pass
// column-softmax (pass A: per-column m,l stats; pass B: normalized PV).
// R1: attn_pv rewritten with LDS-staged, double-buffered K/V tiles
//     (global_load_lds + XOR swizzle) + shfl-broadcast stats.
// ---------------------------------------------------------------------------

#define T_SEQ 2048
#define NBATCH 4

typedef __attribute__((ext_vector_type(8))) short short8;  // 8 x bf16 (4 VGPR)
typedef __attribute__((ext_vector_type(4))) float f32x4;   // MFMA 16x16 acc

typedef __attribute__((address_space(1))) unsigned int g_u32;
typedef __attribute__((address_space(3))) unsigned int l_u32;

__device__ __forceinline__ unsigned short f2bf(float f) {
  union { float f; unsigned u; } x; x.f = f;
  unsigned r = (x.u + 0x7FFFu + ((x.u >> 16) & 1u)) >> 16;  // RNE
  return (unsigned short)r;
}

__device__ __forceinline__ void g2lds16(const void* g, void* l) {
  // async global->LDS, 16B/lane; LDS dest is wave-uniform base + lane*16
  __builtin_amdgcn_global_load_lds((g_u32*)g, (l_u32*)l, 16, 0, 0);
}

// ---------------------------------------------------------------------------
// Generic bf16 GEMM: C[M,N] = A[M,K] @ Bt[N,K]^T   (Bt is B transposed)
// EPI 0: out bf16 = acc            (QKV)
// EPI 1: out f32  = acc + bias[n] + resid[m,n]   (Wo-resid, FFN2-resid)
// EPI 2: out bf16 = relu(acc + bias[n])          (FFN1)
// ---------------------------------------------------------------------------
template <int EPI>
__global__ __launch_bounds__(256) void gemm_bt(
    const unsigned short* __restrict__ A, const unsigned short* __restrict__ Bt,
    int M, int N, int K,
    unsigned short* __restrict__ out16, float* __restrict__ outF,
    const float* __restrict__ bias, const float* __restrict__ resid) {
  __shared__ unsigned short ldsA[128 * 64];
  __shared__ unsigned short ldsB[128 * 64];
  const int tid = threadIdx.x;
  const int lane = tid & 63, wid = tid >> 6;
  const int wm = wid >> 1, wn = wid & 1;
  const int mBase = blockIdx.y * 128, nBase = blockIdx.x * 128;

  f32x4 acc[4][4];
#pragma unroll
  for (int i = 0; i < 4; ++i)
#pragma unroll
    for (int j = 0; j < 4; ++j)
#pragma unroll
      for (int e = 0; e < 4; ++e) acc[i][j][e] = 0.f;

  const int nKT = K >> 6;
  for (int kt = 0; kt < nKT; ++kt) {
    const int k0 = kt << 6;
#pragma unroll
    for (int it = 0; it < 4; ++it) {
      int g = it * 256 + wid * 64 + lane;     // granule id 0..1023 (16B each)
      int row = g >> 3, colL = g & 7;
      int col = colL ^ (row & 7);             // inverse-swizzled source
      g2lds16(A + ((size_t)(mBase + row) * K + k0 + col * 8),
              &ldsA[(it * 256 + wid * 64) * 8]);
      g2lds16(Bt + ((size_t)(nBase + row) * K + k0 + col * 8),
              &ldsB[(it * 256 + wid * 64) * 8]);
    }
    __syncthreads();  // drains vmcnt -> tiles visible

    short8 af[4][2], bf[4][2];
#pragma unroll
    for (int fm = 0; fm < 4; ++fm)
#pragma unroll
      for (int ks = 0; ks < 2; ++ks) {
        int r = wm * 64 + fm * 16 + (lane & 15);
        int c = (ks * 4 + (lane >> 4)) ^ (r & 7);  // swizzled read
        af[fm][ks] = *(const short8*)&ldsA[r * 64 + c * 8];
      }
#pragma unroll
    for (int fn = 0; fn < 4; ++fn)
#pragma unroll
      for (int ks = 0; ks < 2; ++ks) {
        int r = wn * 64 + fn * 16 + (lane & 15);
        int c = (ks * 4 + (lane >> 4)) ^ (r & 7);
        bf[fn][ks] = *(const short8*)&ldsB[r * 64 + c * 8];
      }
#pragma unroll
    for (int fm = 0; fm < 4; ++fm)
#pragma unroll
      for (int fn = 0; fn < 4; ++fn)
#pragma unroll
        for (int ks = 0; ks < 2; ++ks)
          acc[fm][fn] = __builtin_amdgcn_mfma_f32_16x16x32_bf16(
              af[fm][ks], bf[fn][ks], acc[fm][fn], 0, 0, 0);
    __syncthreads();  // before next stage overwrites LDS
  }

#pragma unroll
  for (int fm = 0; fm < 4; ++fm)
#pragma unroll
    for (int fn = 0; fn < 4; ++fn) {
      int col = nBase + wn * 64 + fn * 16 + (lane & 15);
      int row0 = mBase + wm * 64 + fm * 16 + ((lane >> 4) << 2);
      if (EPI == 0) {
#pragma unroll
        for (int r = 0; r < 4; ++r)
          out16[(size_t)(row0 + r) * N + col] = f2bf(acc[fm][fn][r]);
      } else if (EPI == 1) {
        float bv = bias[col];
#pragma unroll
        for (int r = 0; r < 4; ++r) {
          size_t idx = (size_t)(row0 + r) * N + col;
          outF[idx] = acc[fm][fn][r] + bv + resid[idx];
        }
      } else {
        float bv = bias[col];
#pragma unroll
        for (int r = 0; r < 4; ++r)
          out16[(size_t)(row0 + r) * N + col] =
              f2bf(fmaxf(acc[fm][fn][r] + bv, 0.f));
      }
    }
}

// ---------------------------------------------------------------------------
// LayerNorm + bf16 cast.  One block per row of 1024.
// ---------------------------------------------------------------------------
__global__ __launch_bounds__(256) void ln_bf16(
    const float* __restrict__ x, const float* __restrict__ gw,
    const float* __restrict__ bw, unsigned short* __restrict__ out) {
  __shared__ float red[8];
  const int row = blockIdx.x, tid = threadIdx.x;
  const float4 v = ((const float4*)(x + (size_t)row * 1024))[tid];
  float s = v.x + v.y + v.z + v.w;
  float q = v.x * v.x + v.y * v.y + v.z * v.z + v.w * v.w;
#pragma unroll
  for (int off = 32; off >= 1; off >>= 1) {
    s += __shfl_down(s, off);
    q += __shfl_down(q, off);
  }
  const int lane = tid & 63, wid = tid >> 6;
  if (lane == 0) { red[wid] = s; red[4 + wid] = q; }
  __syncthreads();
  float S = red[0] + red[1] + red[2] + red[3];
  float Q = red[4] + red[5] + red[6] + red[7];
  float mu = S * (1.f / 1024.f);
  float var = Q * (1.f / 1024.f) - mu * mu;
  float rs = rsqrtf(var + 1e-5f);
  int c = tid * 4;
  ushort4 ov;
  ov.x = f2bf((v.x - mu) * rs * gw[c + 0] + bw[c + 0]);
  ov.y = f2bf((v.y - mu) * rs * gw[c + 1] + bw[c + 1]);
  ov.z = f2bf((v.z - mu) * rs * gw[c + 2] + bw[c + 2]);
  ov.w = f2bf((v.w - mu) * rs * gw[c + 3] + bw[c + 3]);
  *(ushort4*)&out[(size_t)row * 1024 + c] = ov;
}

// ---------------------------------------------------------------------------
// Weight packing: per-head Wq/Wk/Wv [H,C,HS] f32 -> Wqkv bf16 [3072][1024]
// ---------------------------------------------------------------------------
__global__ __launch_bounds__(256) void pack_qkv(
    const float* __restrict__ Wq, const float* __restrict__ Wk,
    const float* __restrict__ Wv, unsigned short* __restrict__ out) {
  __shared__ float tile[64 * 65];
  const int tid = threadIdx.x;
  const float* W = (blockIdx.z == 0) ? Wq : (blockIdx.z == 1) ? Wk : Wv;
  const int h = blockIdx.y, r0 = blockIdx.x * 64;
#pragma unroll
  for (int it = 0; it < 4; ++it) {
    int e4 = it * 256 + tid;
    int r = e4 >> 4, c4 = e4 & 15;
    float4 v = *(const float4*)&W[((size_t)h * 1024 + r0 + r) * 64 + c4 * 4];
    tile[r * 65 + c4 * 4 + 0] = v.x;
    tile[r * 65 + c4 * 4 + 1] = v.y;
    tile[r * 65 + c4 * 4 + 2] = v.z;
    tile[r * 65 + c4 * 4 + 3] = v.w;
  }
  __syncthreads();
#pragma unroll
  for (int it = 0; it < 4; ++it) {
    int e4 = it * 256 + tid;
    int d = e4 >> 4, r4 = e4 & 15;
    ushort4 ov;
    ov.x = f2bf(tile[(r4 * 4 + 0) * 65 + d]);
    ov.y = f2bf(tile[(r4 * 4 + 1) * 65 + d]);
    ov.z = f2bf(tile[(r4 * 4 + 2) * 65 + d]);
    ov.w = f2bf(tile[(r4 * 4 + 3) * 65 + d]);
    *(ushort4*)&out[(size_t)(blockIdx.z * 1024 + h * 64 + d) * 1024 + r0 +
                    r4 * 4] = ov;
  }
}

// Generic transpose+cast: in f32 [R,C] -> out bf16 [C,R].  grid (R/64, C/64).
__global__ __launch_bounds__(256) void transpose_cast(
    const float* __restrict__ in, unsigned short* __restrict__ out, int R,
    int C) {
  __shared__ float tile[64 * 65];
  const int tid = threadIdx.x;
  const int r0 = blockIdx.x * 64, c0 = blockIdx.y * 64;
#pragma unroll
  for (int it = 0; it < 4; ++it) {
    int e4 = it * 256 + tid;
    int r = e4 >> 4, c4 = e4 & 15;
    float4 v = *(const float4*)&in[(size_t)(r0 + r) * C + c0 + c4 * 4];
    tile[r * 65 + c4 * 4 + 0] = v.x;
    tile[r * 65 + c4 * 4 + 1] = v.y;
    tile[r * 65 + c4 * 4 + 2] = v.z;
    tile[r * 65 + c4 * 4 + 3] = v.w;
  }
  __syncthreads();
#pragma unroll
  for (int it = 0; it < 4; ++it) {
    int e4 = it * 256 + tid;
    int c = e4 >> 4, r4 = e4 & 15;
    ushort4 ov;
    ov.x = f2bf(tile[(r4 * 4 + 0) * 65 + c]);
    ov.y = f2bf(tile[(r4 * 4 + 1) * 65 + c]);
    ov.z = f2bf(tile[(r4 * 4 + 2) * 65 + c]);
    ov.w = f2bf(tile[(r4 * 4 + 3) * 65 + c]);
    *(ushort4*)&out[(size_t)(c0 + c) * R + r0 + r4 * 4] = ov;
  }
}

// V slice of qkv [B,T,3072] (cols 2048..3071) -> vT bf16 [B*H*64][T]
__global__ __launch_bounds__(256) void vtrans(
    const unsigned short* __restrict__ qkv, unsigned short* __restrict__ vT) {
  __shared__ unsigned short tile[64 * 66];
  const int tid = threadIdx.x;
  const int bh = blockIdx.y, b = bh >> 4, h = bh & 15;
  const int t0 = blockIdx.x * 64;
#pragma unroll
  for (int it = 0; it < 8; ++it) {
    int e2 = it * 256 + tid;
    int r = e2 >> 5, c2 = e2 & 31;
    unsigned v = *(const unsigned*)&qkv[(size_t)(b * T_SEQ + t0 + r) * 3072 +
                                        2048 + h * 64 + c2 * 2];
    *(unsigned*)&tile[r * 66 + c2 * 2] = v;
  }
  __syncthreads();
#pragma unroll
  for (int it = 0; it < 8; ++it) {
    int e2 = it * 256 + tid;
    int d = e2 >> 5, t2 = e2 & 31;
    unsigned short a = tile[(t2 * 2) * 66 + d];
    unsigned short bb = tile[(t2 * 2 + 1) * 66 + d];
    unsigned pk = (unsigned)a | ((unsigned)bb << 16);
    *(unsigned*)&vT[(size_t)(bh * 64 + d) * T_SEQ + t0 + t2 * 2] = pk;
  }
}

// ---------------------------------------------------------------------------
// Attention pass A: per-column softmax stats over the QUERY axis.
// ---------------------------------------------------------------------------
__global__ __launch_bounds__(64) void attn_stats(
    const unsigned short* __restrict__ qkv, float* __restrict__ mOut,
    float* __restrict__ linvOut) {
  const int lane = threadIdx.x;
  const int bh = blockIdx.y, b = bh >> 4, h = bh & 15;
  const int s0 = blockIdx.x * 64;
  short8 kf[4][2];
#pragma unroll
  for (int fn = 0; fn < 4; ++fn)
#pragma unroll
    for (int ks = 0; ks < 2; ++ks) {
      int s = s0 + fn * 16 + (lane & 15);
      kf[fn][ks] = *(const short8*)&qkv[(size_t)(b * T_SEQ + s) * 3072 + 1024 +
                                        h * 64 + ks * 32 + ((lane >> 4) << 3)];
    }
  float mcol[4], lcol[4];
#pragma unroll
  for (int fn = 0; fn < 4; ++fn) {
    mcol[fn] = -__builtin_inff();
    lcol[fn] = 0.f;
  }
  for (int t0 = s0; t0 < T_SEQ; t0 += 16) {
    short8 qf[2];
#pragma unroll
    for (int ks = 0; ks < 2; ++ks) {
      int t = t0 + (lane & 15);
      qf[ks] = *(const short8*)&qkv[(size_t)(b * T_SEQ + t) * 3072 + h * 64 +
                                    ks * 32 + ((lane >> 4) << 3)];
    }
    f32x4 sc[4];
#pragma unroll
    for (int fn = 0; fn < 4; ++fn)
#pragma unroll
      for (int e = 0; e < 4; ++e) sc[fn][e] = 0.f;
#pragma unroll
    for (int fn = 0; fn < 4; ++fn)
#pragma unroll
      for (int ks = 0; ks < 2; ++ks)
        sc[fn] = __builtin_amdgcn_mfma_f32_16x16x32_bf16(qf[ks], kf[fn][ks],
                                                         sc[fn], 0, 0, 0);
    const int tRow = t0 + ((lane >> 4) << 2);
#pragma unroll
    for (int fn = 0; fn < 4; ++fn) {
      int s = s0 + fn * 16 + (lane & 15);
      float w[4];
#pragma unroll
      for (int r = 0; r < 4; ++r) {
        float ws = sc[fn][r] * 0.125f;
        w[r] = (tRow + r >= s) ? ws : -__builtin_inff();
      }
      float tmax = fmaxf(fmaxf(w[0], w[1]), fmaxf(w[2], w[3]));
      float mn = fmaxf(mcol[fn], tmax);
      if (mn != -__builtin_inff()) {
        float lsum = __expf(w[0] - mn) + __expf(w[1] - mn) +
                     __expf(w[2] - mn) + __expf(w[3] - mn);
        lcol[fn] = lcol[fn] * __expf(mcol[fn] - mn) + lsum;
        mcol[fn] = mn;
      }
    }
  }
#pragma unroll
  for (int fn = 0; fn < 4; ++fn) {
#pragma unroll
    for (int off = 32; off >= 16; off >>= 1) {
      float mo = __shfl_down(mcol[fn], off);
      float lo = __shfl_down(lcol[fn], off);
      float mn = fmaxf(mcol[fn], mo);
      if (mn != -__builtin_inff()) {
        lcol[fn] = lcol[fn] * __expf(mcol[fn] - mn) + lo * __expf(mo - mn);
        mcol[fn] = mn;
      }
    }
  }
  if (lane < 16) {
#pragma unroll
    for (int fn = 0; fn < 4; ++fn) {
      int s = s0 + fn * 16 + lane;
      mOut[(size_t)bh * T_SEQ + s] = mcol[fn];
      linvOut[(size_t)bh * T_SEQ + s] = 1.f / lcol[fn];
    }
  }
}

// ---------------------------------------------------------------------------
// Attention pass B (R1): O[t,:] = sum_s exp(S[t,s]-m[s])*linv[s] * V[s,:]
// 128 q-rows/block (4 waves x 32 rows), s-tiles of 64.
// K and V tiles staged into double-buffered LDS via global_load_lds with
// pre-swizzled source + XOR-swizzled ds_read (rule #21).  Stats via one
// coalesced 64-float load + __shfl broadcast.  P exchanged through a
// XOR-swizzled LDS tile (0 bank conflicts measured in R0).
// ---------------------------------------------------------------------------
__global__ __launch_bounds__(256) void attn_pv(
    const unsigned short* __restrict__ qkv, const unsigned short* __restrict__ vT,
    const float* __restrict__ mIn, const float* __restrict__ linvIn,
    unsigned short* __restrict__ o) {
  __shared__ unsigned short kbuf[2][64 * 64];
  __shared__ unsigned short vbuf[2][64 * 64];
  __shared__ unsigned short pl[128 * 64];
  const int tid = threadIdx.x, lane = tid & 63, wid = tid >> 6;
  const int bh = blockIdx.y, b = bh >> 4, h = bh & 15;
  const int t0 = blockIdx.x * 128;

  // Q fragments for this wave's 32 rows (held in regs for the whole block)
  short8 qf[2][2];
#pragma unroll
  for (int mf = 0; mf < 2; ++mf)
#pragma unroll
    for (int ks = 0; ks < 2; ++ks) {
      int t = t0 + wid * 32 + mf * 16 + (lane & 15);
      qf[mf][ks] = *(const short8*)&qkv[(size_t)(b * T_SEQ + t) * 3072 + h * 64 +
                                        ks * 32 + ((lane >> 4) << 3)];
    }
  f32x4 oacc[2][4];
#pragma unroll
  for (int i = 0; i < 2; ++i)
#pragma unroll
    for (int j = 0; j < 4; ++j)
#pragma unroll
      for (int e = 0; e < 4; ++e) oacc[i][j][e] = 0.f;

  // cooperative stage of one 64x64 K-tile + 64x64 V-tile into LDS buf
  auto stage = [&](int buf, int st) {
#pragma unroll
    for (int it = 0; it < 2; ++it) {
      int g = it * 256 + tid;            // granule 0..511 (16B each)
      int row = g >> 3, colL = g & 7;
      int col = colL ^ (row & 7);        // inverse-swizzled source
      g2lds16(qkv + ((size_t)(b * T_SEQ + st * 64 + row) * 3072 + 1024 +
                     h * 64 + col * 8),
              &kbuf[buf][(it * 256 + wid * 64) * 8]);
      g2lds16(vT + ((size_t)(bh * 64 + row) * T_SEQ + st * 64 + col * 8),
              &vbuf[buf][(it * 256 + wid * 64) * 8]);
    }
  };

  const int nST = (t0 >> 6) + 2;
  stage(0, 0);
  int cur = 0;
  __syncthreads();  // tile 0 resident (syncthreads drains vmcnt)

  for (int st = 0; st < nST; ++st) {
    const int s0 = st * 64;
    // per-column stats: one coalesced load, broadcast via shfl
    float mv = mIn[(size_t)bh * T_SEQ + s0 + lane];
    float lv = linvIn[(size_t)bh * T_SEQ + s0 + lane];

    // ---- QK^T from LDS K-tile ----
    f32x4 sc[2][4];
#pragma unroll
    for (int i = 0; i < 2; ++i)
#pragma unroll
      for (int j = 0; j < 4; ++j)
#pragma unroll
        for (int e = 0; e < 4; ++e) sc[i][j][e] = 0.f;
#pragma unroll
    for (int fn = 0; fn < 4; ++fn)
#pragma unroll
      for (int ks = 0; ks < 2; ++ks) {
        int r = fn * 16 + (lane & 15);
        int c = (ks * 4 + (lane >> 4)) ^ (r & 7);
        short8 kfr = *(const short8*)&kbuf[cur][r * 64 + c * 8];
        sc[0][fn] = __builtin_amdgcn_mfma_f32_16x16x32_bf16(qf[0][ks], kfr,
                                                            sc[0][fn], 0, 0, 0);
        sc[1][fn] = __builtin_amdgcn_mfma_f32_16x16x32_bf16(qf[1][ks], kfr,
                                                            sc[1][fn], 0, 0, 0);
      }
    // ---- normalize -> bf16 P into swizzled LDS ----
#pragma unroll
    for (int fn = 0; fn < 4; ++fn) {
      float mc = __shfl(mv, fn * 16 + (lane & 15));
      float li = __shfl(lv, fn * 16 + (lane & 15));
      int sg = s0 + fn * 16 + (lane & 15);
#pragma unroll
      for (int mf = 0; mf < 2; ++mf) {
        int rowB = wid * 32 + mf * 16 + ((lane >> 4) << 2);
        int colB = fn * 16 + (lane & 15);
#pragma unroll
        for (int r = 0; r < 4; ++r) {
          int t = t0 + rowB + r;
          float p =
              (t >= sg) ? __expf(sc[mf][fn][r] * 0.125f - mc) * li : 0.f;
          int byteoff =
              (rowB + r) * 128 + ((colB * 2) ^ (((rowB + r) & 7) << 4));
          *(unsigned short*)((char*)pl + byteoff) = f2bf(p);
        }
      }
    }
    __syncthreads();  // pl ready (prev stage already drained before this tile)

    // prefetch next K/V tile; overlaps the PV phase, drained by end barrier
    if (st + 1 < nST) stage(cur ^ 1, st + 1);

    // ---- PV: A = P (LDS, swizzled), B^T = V-tile rows (LDS, swizzled) ----
#pragma unroll
    for (int ks = 0; ks < 2; ++ks) {
      short8 pa[2];
#pragma unroll
      for (int mf = 0; mf < 2; ++mf) {
        int row = wid * 32 + mf * 16 + (lane & 15);
        int bo = row * 128 +
                 ((ks * 64 + ((lane >> 4) << 4)) ^ ((row & 7) << 4));
        pa[mf] = *(const short8*)((const char*)pl + bo);
      }
#pragma unroll
      for (int df = 0; df < 4; ++df) {
        int r = df * 16 + (lane & 15);
        int c = (ks * 4 + (lane >> 4)) ^ (r & 7);
        short8 vb = *(const short8*)&vbuf[cur][r * 64 + c * 8];
        oacc[0][df] = __builtin_amdgcn_mfma_f32_16x16x32_bf16(pa[0], vb,
                                                              oacc[0][df], 0, 0, 0);
        oacc[1][df] = __builtin_amdgcn_mfma_f32_16x16x32_bf16(pa[1], vb,
                                                              oacc[1][df], 0, 0, 0);
      }
    }
    __syncthreads();  // drains prefetch; pl free for next tile
    cur ^= 1;
  }
  // write O as bf16 [B,T,C] (c = h*64+d)
#pragma unroll
  for (int mf = 0; mf < 2; ++mf)
#pragma unroll
    for (int df = 0; df < 4; ++df) {
      int d = df * 16 + (lane & 15);
      int row0 = t0 + wid * 32 + mf * 16 + ((lane >> 4) << 2);
#pragma unroll
      for (int r = 0; r < 4; ++r)
        o[(size_t)(b * T_SEQ + row0 + r) * 1024 + h * 64 + d] =
            f2bf(oacc[mf][df][r]);
    }
}

// ---------------------------------------------------------------------------
extern "C" void kernel_launch(void* const* d_in, const int* in_sizes, int n_in,
                              void* d_out, int out_size, void* d_ws,
                              size_t ws_size, hipStream_t stream) {
  const float* x = (const float*)d_in[0];
  const float* Wq = (const float*)d_in[1];
  const float* Wk = (const float*)d_in[2];
  const float* Wv = (const float*)d_in[3];
  const float* Wo = (const float*)d_in[4];
  const float* bo = (const float*)d_in[5];
  const float* g1 = (const float*)d_in[6];
  const float* b1 = (const float*)d_in[7];
  const float* g2 = (const float*)d_in[8];
  const float* b2 = (const float*)d_in[9];
  const float* W1 = (const float*)d_in[10];
  const float* bf1 = (const float*)d_in[11];
  const float* W2 = (const float*)d_in[12];
  const float* bf2 = (const float*)d_in[13];
  float* out = (float*)d_out;

  char* ws = (char*)d_ws;
  size_t off = 0;
  auto alloc = [&](size_t bytes) {
    char* p = ws + off;
    off += (bytes + 255) & ~(size_t)255;
    return p;
  };
  unsigned short* Wqkv = (unsigned short*)alloc(3072ull * 1024 * 2);
  unsigned short* WoT = (unsigned short*)alloc(1024ull * 1024 * 2);
  unsigned short* W1T = (unsigned short*)alloc(4096ull * 1024 * 2);
  unsigned short* W2T = (unsigned short*)alloc(1024ull * 4096 * 2);
  unsigned short* hbuf = (unsigned short*)alloc(8192ull * 1024 * 2);  // h, then o
  char* regionE = alloc(8192ull * 3072 * 2 + 64ull * 64 * 2048 * 2);
  unsigned short* qkv = (unsigned short*)regionE;           // live: QKV..attn
  unsigned short* vT = (unsigned short*)(regionE + 8192ull * 3072 * 2);
  unsigned short* act = (unsigned short*)regionE;           // live: FFN (after attn)
  float* mbuf = (float*)alloc(64ull * 2048 * 4);
  float* lbuf = (float*)alloc(64ull * 2048 * 4);
  float* x1 = (float*)alloc(8192ull * 1024 * 4);
  unsigned short* fbuf = (unsigned short*)alloc(8192ull * 1024 * 2);
  unsigned short* obuf = hbuf;  // h dead after QKV GEMM

  (void)in_sizes; (void)n_in; (void)out_size; (void)ws_size;

  // weight packing (B^T bf16 layouts)
  pack_qkv<<<dim3(16, 16, 3), 256, 0, stream>>>(Wq, Wk, Wv, Wqkv);
  transpose_cast<<<dim3(16, 16), 256, 0, stream>>>(Wo, WoT, 1024, 1024);
  transpose_cast<<<dim3(16, 64), 256, 0, stream>>>(W1, W1T, 1024, 4096);
  transpose_cast<<<dim3(64, 16), 256, 0, stream>>>(W2, W2T, 4096, 1024);
  // LN1 -> h
  ln_bf16<<<8192, 256, 0, stream>>>(x, g1, b1, hbuf);
  // QKV projection: [8192,1024]@[1024,3072]
  gemm_bt<0><<<dim3(24, 64), 256, 0, stream>>>(hbuf, Wqkv, 8192, 3072, 1024,
                                               qkv, nullptr, nullptr, nullptr);
  // V transpose for PV B-operand
  vtrans<<<dim3(32, 64), 256, 0, stream>>>(qkv, vT);
  // attention
  attn_stats<<<dim3(32, 64), 64, 0, stream>>>(qkv, mbuf, lbuf);
  attn_pv<<<dim3(16, 64), 256, 0, stream>>>(qkv, vT, mbuf, lbuf, obuf);
  // x1 = x + O@Wo + bo
  gemm_bt<1><<<dim3(8, 64), 256, 0, stream>>>(obuf, WoT, 8192, 1024, 1024,
                                              nullptr, x1, bo, x);
  // LN2 -> f
  ln_bf16<<<8192, 256, 0, stream>>>(x1, g2, b2, fbuf);
  // FFN1: relu(f@W1 + bf1) -> act bf16 [8192,4096]
  gemm_bt<2><<<dim3(32, 64), 256, 0, stream>>>(fbuf, W1T, 8192, 4096, 1024, act,
                                               nullptr, bf1, nullptr);
  // FFN2 + residual: out = x1 + act@W2 + bf2
  gemm_bt<1><<<dim3(8, 64), 256, 0, stream>>>(act, W2T, 8192, 1024, 4096,
                                              nullptr, out, bf2, x1);
}

// Round 3
// 471.678 us; speedup vs baseline: 1.8520x; 1.3045x over previous
//
#include <hip/hip_runtime.h>

// ---------------------------------------------------------------------------
// Transformer block fwd (B=4,T=2048,C=1024,H=16,HS=64,FF=4096), fp32 in/out,
// bf16 MFMA internally.  Softmax is over the QUERY axis (axis=-2): two-pass
// column-softmax.  R3: pass A = maxless sum-of-exp2 (bounded scores), 4-wave
// paired-column blocks w/ per-wave double-buffered LDS Q staging; pass B =
// paired row-tiles (load balance) sharing K/V staging, setprio on MFMA.
// ---------------------------------------------------------------------------

#define T_SEQ 2048
#define SCALE2 0.1803368801f  // 0.125 * log2(e): p = 2^(s*SCALE2) == e^(s/8)

typedef __attribute__((ext_vector_type(8))) short short8;  // 8 x bf16 (4 VGPR)
typedef __attribute__((ext_vector_type(4))) float f32x4;   // MFMA 16x16 acc

typedef __attribute__((address_space(1))) unsigned int g_u32;
typedef __attribute__((address_space(3))) unsigned int l_u32;

__device__ __forceinline__ unsigned short f2bf(float f) {
  union { float f; unsigned u; } x; x.f = f;
  unsigned r = (x.u + 0x7FFFu + ((x.u >> 16) & 1u)) >> 16;  // RNE
  return (unsigned short)r;
}

__device__ __forceinline__ void g2lds16(const void* g, void* l) {
  // async global->LDS, 16B/lane; LDS dest is wave-uniform base + lane*16
  __builtin_amdgcn_global_load_lds((g_u32*)g, (l_u32*)l, 16, 0, 0);
}

// ---------------------------------------------------------------------------
// Generic bf16 GEMM: C[M,N] = A[M,K] @ Bt[N,K]^T   (Bt is B transposed)
// EPI 0: out bf16 = acc            (QKV)
// EPI 1: out f32  = acc + bias[n] + resid[m,n]   (Wo-resid, FFN2-resid)
// EPI 2: out bf16 = relu(acc + bias[n])          (FFN1)
// ---------------------------------------------------------------------------
template <int EPI>
__global__ __launch_bounds__(256) void gemm_bt(
    const unsigned short* __restrict__ A, const unsigned short* __restrict__ Bt,
    int M, int N, int K,
    unsigned short* __restrict__ out16, float* __restrict__ outF,
    const float* __restrict__ bias, const float* __restrict__ resid) {
  __shared__ unsigned short ldsA[128 * 64];
  __shared__ unsigned short ldsB[128 * 64];
  const int tid = threadIdx.x;
  const int lane = tid & 63, wid = tid >> 6;
  const int wm = wid >> 1, wn = wid & 1;
  const int mBase = blockIdx.y * 128, nBase = blockIdx.x * 128;

  f32x4 acc[4][4];
#pragma unroll
  for (int i = 0; i < 4; ++i)
#pragma unroll
    for (int j = 0; j < 4; ++j)
#pragma unroll
      for (int e = 0; e < 4; ++e) acc[i][j][e] = 0.f;

  const int nKT = K >> 6;
  for (int kt = 0; kt < nKT; ++kt) {
    const int k0 = kt << 6;
#pragma unroll
    for (int it = 0; it < 4; ++it) {
      int g = it * 256 + wid * 64 + lane;     // granule id 0..1023 (16B each)
      int row = g >> 3, colL = g & 7;
      int col = colL ^ (row & 7);             // inverse-swizzled source
      g2lds16(A + ((size_t)(mBase + row) * K + k0 + col * 8),
              &ldsA[(it * 256 + wid * 64) * 8]);
      g2lds16(Bt + ((size_t)(nBase + row) * K + k0 + col * 8),
              &ldsB[(it * 256 + wid * 64) * 8]);
    }
    __syncthreads();  // drains vmcnt -> tiles visible

    short8 af[4][2], bf[4][2];
#pragma unroll
    for (int fm = 0; fm < 4; ++fm)
#pragma unroll
      for (int ks = 0; ks < 2; ++ks) {
        int r = wm * 64 + fm * 16 + (lane & 15);
        int c = (ks * 4 + (lane >> 4)) ^ (r & 7);  // swizzled read
        af[fm][ks] = *(const short8*)&ldsA[r * 64 + c * 8];
      }
#pragma unroll
    for (int fn = 0; fn < 4; ++fn)
#pragma unroll
      for (int ks = 0; ks < 2; ++ks) {
        int r = wn * 64 + fn * 16 + (lane & 15);
        int c = (ks * 4 + (lane >> 4)) ^ (r & 7);
        bf[fn][ks] = *(const short8*)&ldsB[r * 64 + c * 8];
      }
#pragma unroll
    for (int fm = 0; fm < 4; ++fm)
#pragma unroll
      for (int fn = 0; fn < 4; ++fn)
#pragma unroll
        for (int ks = 0; ks < 2; ++ks)
          acc[fm][fn] = __builtin_amdgcn_mfma_f32_16x16x32_bf16(
              af[fm][ks], bf[fn][ks], acc[fm][fn], 0, 0, 0);
    __syncthreads();  // before next stage overwrites LDS
  }

#pragma unroll
  for (int fm = 0; fm < 4; ++fm)
#pragma unroll
    for (int fn = 0; fn < 4; ++fn) {
      int col = nBase + wn * 64 + fn * 16 + (lane & 15);
      int row0 = mBase + wm * 64 + fm * 16 + ((lane >> 4) << 2);
      if (EPI == 0) {
#pragma unroll
        for (int r = 0; r < 4; ++r)
          out16[(size_t)(row0 + r) * N + col] = f2bf(acc[fm][fn][r]);
      } else if (EPI == 1) {
        float bv = bias[col];
#pragma unroll
        for (int r = 0; r < 4; ++r) {
          size_t idx = (size_t)(row0 + r) * N + col;
          outF[idx] = acc[fm][fn][r] + bv + resid[idx];
        }
      } else {
        float bv = bias[col];
#pragma unroll
        for (int r = 0; r < 4; ++r)
          out16[(size_t)(row0 + r) * N + col] =
              f2bf(fmaxf(acc[fm][fn][r] + bv, 0.f));
      }
    }
}

// ---------------------------------------------------------------------------
// LayerNorm + bf16 cast.  One block per row of 1024.
// ---------------------------------------------------------------------------
__global__ __launch_bounds__(256) void ln_bf16(
    const float* __restrict__ x, const float* __restrict__ gw,
    const float* __restrict__ bw, unsigned short* __restrict__ out) {
  __shared__ float red[8];
  const int row = blockIdx.x, tid = threadIdx.x;
  const float4 v = ((const float4*)(x + (size_t)row * 1024))[tid];
  float s = v.x + v.y + v.z + v.w;
  float q = v.x * v.x + v.y * v.y + v.z * v.z + v.w * v.w;
#pragma unroll
  for (int off = 32; off >= 1; off >>= 1) {
    s += __shfl_down(s, off);
    q += __shfl_down(q, off);
  }
  const int lane = tid & 63, wid = tid >> 6;
  if (lane == 0) { red[wid] = s; red[4 + wid] = q; }
  __syncthreads();
  float S = red[0] + red[1] + red[2] + red[3];
  float Q = red[4] + red[5] + red[6] + red[7];
  float mu = S * (1.f / 1024.f);
  float var = Q * (1.f / 1024.f) - mu * mu;
  float rs = rsqrtf(var + 1e-5f);
  int c = tid * 4;
  ushort4 ov;
  ov.x = f2bf((v.x - mu) * rs * gw[c + 0] + bw[c + 0]);
  ov.y = f2bf((v.y - mu) * rs * gw[c + 1] + bw[c + 1]);
  ov.z = f2bf((v.z - mu) * rs * gw[c + 2] + bw[c + 2]);
  ov.w = f2bf((v.w - mu) * rs * gw[c + 3] + bw[c + 3]);
  *(ushort4*)&out[(size_t)row * 1024 + c] = ov;
}

// ---------------------------------------------------------------------------
// Weight packing: per-head Wq/Wk/Wv [H,C,HS] f32 -> Wqkv bf16 [3072][1024]
// ---------------------------------------------------------------------------
__global__ __launch_bounds__(256) void pack_qkv(
    const float* __restrict__ Wq, const float* __restrict__ Wk,
    const float* __restrict__ Wv, unsigned short* __restrict__ out) {
  __shared__ float tile[64 * 65];
  const int tid = threadIdx.x;
  const float* W = (blockIdx.z == 0) ? Wq : (blockIdx.z == 1) ? Wk : Wv;
  const int h = blockIdx.y, r0 = blockIdx.x * 64;
#pragma unroll
  for (int it = 0; it < 4; ++it) {
    int e4 = it * 256 + tid;
    int r = e4 >> 4, c4 = e4 & 15;
    float4 v = *(const float4*)&W[((size_t)h * 1024 + r0 + r) * 64 + c4 * 4];
    tile[r * 65 + c4 * 4 + 0] = v.x;
    tile[r * 65 + c4 * 4 + 1] = v.y;
    tile[r * 65 + c4 * 4 + 2] = v.z;
    tile[r * 65 + c4 * 4 + 3] = v.w;
  }
  __syncthreads();
#pragma unroll
  for (int it = 0; it < 4; ++it) {
    int e4 = it * 256 + tid;
    int d = e4 >> 4, r4 = e4 & 15;
    ushort4 ov;
    ov.x = f2bf(tile[(r4 * 4 + 0) * 65 + d]);
    ov.y = f2bf(tile[(r4 * 4 + 1) * 65 + d]);
    ov.z = f2bf(tile[(r4 * 4 + 2) * 65 + d]);
    ov.w = f2bf(tile[(r4 * 4 + 3) * 65 + d]);
    *(ushort4*)&out[(size_t)(blockIdx.z * 1024 + h * 64 + d) * 1024 + r0 +
                    r4 * 4] = ov;
  }
}

// Generic transpose+cast: in f32 [R,C] -> out bf16 [C,R].  grid (R/64, C/64).
__global__ __launch_bounds__(256) void transpose_cast(
    const float* __restrict__ in, unsigned short* __restrict__ out, int R,
    int C) {
  __shared__ float tile[64 * 65];
  const int tid = threadIdx.x;
  const int r0 = blockIdx.x * 64, c0 = blockIdx.y * 64;
#pragma unroll
  for (int it = 0; it < 4; ++it) {
    int e4 = it * 256 + tid;
    int r = e4 >> 4, c4 = e4 & 15;
    float4 v = *(const float4*)&in[(size_t)(r0 + r) * C + c0 + c4 * 4];
    tile[r * 65 + c4 * 4 + 0] = v.x;
    tile[r * 65 + c4 * 4 + 1] = v.y;
    tile[r * 65 + c4 * 4 + 2] = v.z;
    tile[r * 65 + c4 * 4 + 3] = v.w;
  }
  __syncthreads();
#pragma unroll
  for (int it = 0; it < 4; ++it) {
    int e4 = it * 256 + tid;
    int c = e4 >> 4, r4 = e4 & 15;
    ushort4 ov;
    ov.x = f2bf(tile[(r4 * 4 + 0) * 65 + c]);
    ov.y = f2bf(tile[(r4 * 4 + 1) * 65 + c]);
    ov.z = f2bf(tile[(r4 * 4 + 2) * 65 + c]);
    ov.w = f2bf(tile[(r4 * 4 + 3) * 65 + c]);
    *(ushort4*)&out[(size_t)(c0 + c) * R + r0 + r4 * 4] = ov;
  }
}

// V slice of qkv [B,T,3072] (cols 2048..3071) -> vT bf16 [B*H*64][T]
__global__ __launch_bounds__(256) void vtrans(
    const unsigned short* __restrict__ qkv, unsigned short* __restrict__ vT) {
  __shared__ unsigned short tile[64 * 66];
  const int tid = threadIdx.x;
  const int bh = blockIdx.y, b = bh >> 4, h = bh & 15;
  const int t0 = blockIdx.x * 64;
#pragma unroll
  for (int it = 0; it < 8; ++it) {
    int e2 = it * 256 + tid;
    int r = e2 >> 5, c2 = e2 & 31;
    unsigned v = *(const unsigned*)&qkv[(size_t)(b * T_SEQ + t0 + r) * 3072 +
                                        2048 + h * 64 + c2 * 2];
    *(unsigned*)&tile[r * 66 + c2 * 2] = v;
  }
  __syncthreads();
#pragma unroll
  for (int it = 0; it < 8; ++it) {
    int e2 = it * 256 + tid;
    int d = e2 >> 5, t2 = e2 & 31;
    unsigned short a = tile[(t2 * 2) * 66 + d];
    unsigned short bb = tile[(t2 * 2 + 1) * 66 + d];
    unsigned pk = (unsigned)a | ((unsigned)bb << 16);
    *(unsigned*)&vT[(size_t)(bh * 64 + d) * T_SEQ + t0 + t2 * 2] = pk;
  }
}

// ---------------------------------------------------------------------------
// Attention pass A (R3): l[s] = sum_{t>=s} 2^(S[t,s]*SCALE2)  -- maxless
// (|q.k| <= 64 -> |z| <= ~12, safe in fp32).  Block = 4 waves, handles the
// column-tile pair sA=sx*64, sB=(31-sx)*64 (constant 33 MFMA-units/block).
// Waves split the t-range (stride 4x64); per-wave double-buffered LDS Q
// staging via global_load_lds + counted vmcnt -- no barriers in main loop.
// ---------------------------------------------------------------------------
__global__ __launch_bounds__(256) void attn_stats(
    const unsigned short* __restrict__ qkv, float* __restrict__ linvOut) {
  __shared__ unsigned short qt[4][2][64 * 64];  // per-wave double buffer
  __shared__ float redL[4][2][64];
  const int tid = threadIdx.x, lane = tid & 63, w = tid >> 6;
  const int bh = blockIdx.y, b = bh >> 4, h = bh & 15;
  const int sx = blockIdx.x;
  const int sA = sx * 64, sB = (31 - sx) * 64;
  const int nT = 32 - sx;          // t-tiles from sA to end (>= 17)
  const int bDiag = 31 - 2 * sx;   // idx where t0 == sB

  short8 kfA[4][2], kfB[4][2];
#pragma unroll
  for (int fn = 0; fn < 4; ++fn)
#pragma unroll
    for (int ks = 0; ks < 2; ++ks) {
      int d = 1024 + h * 64 + ks * 32 + ((lane >> 4) << 3);
      kfA[fn][ks] = *(const short8*)&qkv[(size_t)(b * T_SEQ + sA + fn * 16 +
                                                  (lane & 15)) * 3072 + d];
      kfB[fn][ks] = *(const short8*)&qkv[(size_t)(b * T_SEQ + sB + fn * 16 +
                                                  (lane & 15)) * 3072 + d];
    }
  float lA[4] = {0.f, 0.f, 0.f, 0.f}, lB[4] = {0.f, 0.f, 0.f, 0.f};

  auto stageQ = [&](int buf, int idx) {
    int t0 = sA + idx * 64;
#pragma unroll
    for (int it = 0; it < 8; ++it) {
      int g = it * 64 + lane;
      int row = g >> 3;
      int col = (g & 7) ^ (row & 7);  // inverse-swizzled source
      g2lds16(qkv + ((size_t)(b * T_SEQ + t0 + row) * 3072 + h * 64 + col * 8),
              &qt[w][buf][it * 512]);
    }
  };

  auto accum = [&](const short8 (&af)[2], const short8 (&kf)[4][2],
                   float (&lacc)[4], int sBase, int t0, int mf, bool diag) {
    f32x4 sc[4];
#pragma unroll
    for (int fn = 0; fn < 4; ++fn)
#pragma unroll
      for (int e = 0; e < 4; ++e) sc[fn][e] = 0.f;
    __builtin_amdgcn_s_setprio(1);
#pragma unroll
    for (int fn = 0; fn < 4; ++fn)
#pragma unroll
      for (int ks = 0; ks < 2; ++ks)
        sc[fn] = __builtin_amdgcn_mfma_f32_16x16x32_bf16(af[ks], kf[fn][ks],
                                                         sc[fn], 0, 0, 0);
    __builtin_amdgcn_s_setprio(0);
    const int tRow = t0 + mf * 16 + ((lane >> 4) << 2);
    if (diag) {
#pragma unroll
      for (int fn = 0; fn < 4; ++fn) {
        int s = sBase + fn * 16 + (lane & 15);
#pragma unroll
        for (int r = 0; r < 4; ++r) {
          float e = exp2f(sc[fn][r] * SCALE2);
          lacc[fn] += (tRow + r >= s) ? e : 0.f;
        }
      }
    } else {
#pragma unroll
      for (int fn = 0; fn < 4; ++fn)
#pragma unroll
        for (int r = 0; r < 4; ++r) lacc[fn] += exp2f(sc[fn][r] * SCALE2);
    }
  };

  int idx = w, cur = 0;
  stageQ(0, idx);  // nT >= 17 so every wave has work
  for (; idx < nT; idx += 4, cur ^= 1) {
    if (idx + 4 < nT) {
      stageQ(cur ^ 1, idx + 4);
      asm volatile("s_waitcnt vmcnt(8)" ::: "memory");  // cur buf resident
    } else {
      asm volatile("s_waitcnt vmcnt(0)" ::: "memory");
    }
    const int t0 = sA + idx * 64;
    const bool doB = idx >= bDiag;
#pragma unroll
    for (int mf = 0; mf < 4; ++mf) {
      short8 af[2];
#pragma unroll
      for (int ks = 0; ks < 2; ++ks) {
        int r = mf * 16 + (lane & 15);
        int c = (ks * 4 + (lane >> 4)) ^ (r & 7);
        af[ks] = *(const short8*)&qt[w][cur][r * 64 + c * 8];
      }
      accum(af, kfA, lA, sA, t0, mf, idx == 0);
      if (doB) accum(af, kfB, lB, sB, t0, mf, idx == bDiag);
    }
  }
  // combine hi-groups within wave (cols live in lanes l, l+16, l+32, l+48)
#pragma unroll
  for (int fn = 0; fn < 4; ++fn) {
    lA[fn] += __shfl_down(lA[fn], 32);
    lA[fn] += __shfl_down(lA[fn], 16);
    lB[fn] += __shfl_down(lB[fn], 32);
    lB[fn] += __shfl_down(lB[fn], 16);
  }
  if (lane < 16) {
#pragma unroll
    for (int fn = 0; fn < 4; ++fn) {
      redL[w][0][fn * 16 + lane] = lA[fn];
      redL[w][1][fn * 16 + lane] = lB[fn];
    }
  }
  __syncthreads();
  if (tid < 128) {
    int which = tid >> 6;  // 0 -> A, 1 -> B
    float l = redL[0][which][lane] + redL[1][which][lane] +
              redL[2][which][lane] + redL[3][which][lane];
    int sbase = (which == 0) ? sA : sB;
    linvOut[(size_t)bh * T_SEQ + sbase + lane] = 1.f / l;
  }
}

// ---------------------------------------------------------------------------
// Attention pass B (R3): O[t,:] = sum_s 2^(S[t,s]*SCALE2)*linv[s] * V[s,:]
// Block handles row-tile PAIR tA=bx*128, tB=(15-bx)*128 -> constant work,
// K/V staging shared by both tiles (2x compute per staged byte).
// ---------------------------------------------------------------------------
__global__ __launch_bounds__(256, 2) void attn_pv(
    const unsigned short* __restrict__ qkv, const unsigned short* __restrict__ vT,
    const float* __restrict__ linvIn, unsigned short* __restrict__ o) {
  __shared__ unsigned short kbuf[2][64 * 64];
  __shared__ unsigned short vbuf[2][64 * 64];
  __shared__ unsigned short pl[256 * 64];  // rows 0-127: A, 128-255: B
  const int tid = threadIdx.x, lane = tid & 63, wid = tid >> 6;
  const int bh = blockIdx.y, b = bh >> 4, h = bh & 15;
  const int bx = blockIdx.x;
  const int tA = bx * 128, tB = (15 - bx) * 128;
  const int nSTA = 2 * bx + 2, nSTB = 32 - 2 * bx;  // nSTA < nSTB always

  short8 qfA[2][2], qfB[2][2];
#pragma unroll
  for (int mf = 0; mf < 2; ++mf)
#pragma unroll
    for (int ks = 0; ks < 2; ++ks) {
      int d = h * 64 + ks * 32 + ((lane >> 4) << 3);
      int rloc = wid * 32 + mf * 16 + (lane & 15);
      qfA[mf][ks] =
          *(const short8*)&qkv[(size_t)(b * T_SEQ + tA + rloc) * 3072 + d];
      qfB[mf][ks] =
          *(const short8*)&qkv[(size_t)(b * T_SEQ + tB + rloc) * 3072 + d];
    }
  f32x4 oaccA[2][4], oaccB[2][4];
#pragma unroll
  for (int i = 0; i < 2; ++i)
#pragma unroll
    for (int j = 0; j < 4; ++j)
#pragma unroll
      for (int e = 0; e < 4; ++e) { oaccA[i][j][e] = 0.f; oaccB[i][j][e] = 0.f; }

  auto stage = [&](int buf, int st) {
#pragma unroll
    for (int it = 0; it < 2; ++it) {
      int g = it * 256 + tid;            // granule 0..511 (16B each)
      int row = g >> 3, colL = g & 7;
      int col = colL ^ (row & 7);        // inverse-swizzled source
      g2lds16(qkv + ((size_t)(b * T_SEQ + st * 64 + row) * 3072 + 1024 +
                     h * 64 + col * 8),
              &kbuf[buf][(it * 256 + wid * 64) * 8]);
      g2lds16(vT + ((size_t)(bh * 64 + row) * T_SEQ + st * 64 + col * 8),
              &vbuf[buf][(it * 256 + wid * 64) * 8]);
    }
  };

  // QK^T for one row-tile from LDS K-tile, normalize, store P into pl
  auto qkstore = [&](const short8 (&qf)[2][2], int rowBase, int tBase, int s0,
                     float cc, bool maskNeeded, int cur) {
    f32x4 sc[2][4];
#pragma unroll
    for (int i = 0; i < 2; ++i)
#pragma unroll
      for (int j = 0; j < 4; ++j)
#pragma unroll
        for (int e = 0; e < 4; ++e) sc[i][j][e] = 0.f;
    __builtin_amdgcn_s_setprio(1);
#pragma unroll
    for (int fn = 0; fn < 4; ++fn)
#pragma unroll
      for (int ks = 0; ks < 2; ++ks) {
        int r = fn * 16 + (lane & 15);
        int c = (ks * 4 + (lane >> 4)) ^ (r & 7);
        short8 kfr = *(const short8*)&kbuf[cur][r * 64 + c * 8];
        sc[0][fn] = __builtin_amdgcn_mfma_f32_16x16x32_bf16(qf[0][ks], kfr,
                                                            sc[0][fn], 0, 0, 0);
        sc[1][fn] = __builtin_amdgcn_mfma_f32_16x16x32_bf16(qf[1][ks], kfr,
                                                            sc[1][fn], 0, 0, 0);
      }
    __builtin_amdgcn_s_setprio(0);
#pragma unroll
    for (int fn = 0; fn < 4; ++fn) {
      float ccf = __shfl(cc, fn * 16 + (lane & 15));
      int sg = s0 + fn * 16 + (lane & 15);
      int colb = (fn * 16 + (lane & 15)) * 2;
#pragma unroll
      for (int mf = 0; mf < 2; ++mf) {
        int rowB = rowBase + wid * 32 + mf * 16 + ((lane >> 4) << 2);
        int tRow = tBase + wid * 32 + mf * 16 + ((lane >> 4) << 2);
#pragma unroll
        for (int r = 0; r < 4; ++r) {
          float p = exp2f(fmaf(sc[mf][fn][r], SCALE2, ccf));
          if (maskNeeded) p = (tRow + r >= sg) ? p : 0.f;
          int row = rowB + r;
          int byteoff = row * 128 + (colb ^ ((row & 7) << 4));
          *(unsigned short*)((char*)pl + byteoff) = f2bf(p);
        }
      }
    }
  };

  stage(0, 0);
  int cur = 0;
  __syncthreads();  // tile 0 resident

  for (int st = 0; st < nSTB; ++st) {
    const int s0 = st * 64;
    float lv = linvIn[(size_t)bh * T_SEQ + s0 + lane];
    float cc = __log2f(lv);
    const bool doA = st < nSTA;

    if (doA) qkstore(qfA, 0, tA, s0, cc, st >= nSTA - 2, cur);
    qkstore(qfB, 128, tB, s0, cc, st >= nSTB - 2, cur);
    __syncthreads();  // pl ready

    if (st + 1 < nSTB) stage(cur ^ 1, st + 1);  // overlaps PV

    __builtin_amdgcn_s_setprio(1);
#pragma unroll
    for (int ks = 0; ks < 2; ++ks) {
      short8 paA[2], paB[2];
#pragma unroll
      for (int mf = 0; mf < 2; ++mf) {
        int rowa = wid * 32 + mf * 16 + (lane & 15);
        int kb = ks * 64 + ((lane >> 4) << 4);
        paB[mf] = *(const short8*)((const char*)pl + (128 + rowa) * 128 +
                                   (kb ^ ((rowa & 7) << 4)));
        if (doA)
          paA[mf] = *(const short8*)((const char*)pl + rowa * 128 +
                                     (kb ^ ((rowa & 7) << 4)));
      }
#pragma unroll
      for (int df = 0; df < 4; ++df) {
        int r = df * 16 + (lane & 15);
        int c = (ks * 4 + (lane >> 4)) ^ (r & 7);
        short8 vb = *(const short8*)&vbuf[cur][r * 64 + c * 8];
        oaccB[0][df] = __builtin_amdgcn_mfma_f32_16x16x32_bf16(paB[0], vb,
                                                               oaccB[0][df], 0, 0, 0);
        oaccB[1][df] = __builtin_amdgcn_mfma_f32_16x16x32_bf16(paB[1], vb,
                                                               oaccB[1][df], 0, 0, 0);
        if (doA) {
          oaccA[0][df] = __builtin_amdgcn_mfma_f32_16x16x32_bf16(paA[0], vb,
                                                                 oaccA[0][df], 0, 0, 0);
          oaccA[1][df] = __builtin_amdgcn_mfma_f32_16x16x32_bf16(paA[1], vb,
                                                                 oaccA[1][df], 0, 0, 0);
        }
      }
    }
    __builtin_amdgcn_s_setprio(0);
    __syncthreads();  // drains prefetch; pl free
    cur ^= 1;
  }
  // write O as bf16 [B,T,C] (c = h*64+d)
#pragma unroll
  for (int mf = 0; mf < 2; ++mf)
#pragma unroll
    for (int df = 0; df < 4; ++df) {
      int d = h * 64 + df * 16 + (lane & 15);
      int ra = tA + wid * 32 + mf * 16 + ((lane >> 4) << 2);
      int rb = tB + wid * 32 + mf * 16 + ((lane >> 4) << 2);
#pragma unroll
      for (int r = 0; r < 4; ++r) {
        o[(size_t)(b * T_SEQ + ra + r) * 1024 + d] = f2bf(oaccA[mf][df][r]);
        o[(size_t)(b * T_SEQ + rb + r) * 1024 + d] = f2bf(oaccB[mf][df][r]);
      }
    }
}

// ---------------------------------------------------------------------------
extern "C" void kernel_launch(void* const* d_in, const int* in_sizes, int n_in,
                              void* d_out, int out_size, void* d_ws,
                              size_t ws_size, hipStream_t stream) {
  const float* x = (const float*)d_in[0];
  const float* Wq = (const float*)d_in[1];
  const float* Wk = (const float*)d_in[2];
  const float* Wv = (const float*)d_in[3];
  const float* Wo = (const float*)d_in[4];
  const float* bo = (const float*)d_in[5];
  const float* g1 = (const float*)d_in[6];
  const float* b1 = (const float*)d_in[7];
  const float* g2 = (const float*)d_in[8];
  const float* b2 = (const float*)d_in[9];
  const float* W1 = (const float*)d_in[10];
  const float* bf1 = (const float*)d_in[11];
  const float* W2 = (const float*)d_in[12];
  const float* bf2 = (const float*)d_in[13];
  float* out = (float*)d_out;

  char* ws = (char*)d_ws;
  size_t off = 0;
  auto alloc = [&](size_t bytes) {
    char* p = ws + off;
    off += (bytes + 255) & ~(size_t)255;
    return p;
  };
  unsigned short* Wqkv = (unsigned short*)alloc(3072ull * 1024 * 2);
  unsigned short* WoT = (unsigned short*)alloc(1024ull * 1024 * 2);
  unsigned short* W1T = (unsigned short*)alloc(4096ull * 1024 * 2);
  unsigned short* W2T = (unsigned short*)alloc(1024ull * 4096 * 2);
  unsigned short* hbuf = (unsigned short*)alloc(8192ull * 1024 * 2);  // h, then o
  char* regionE = alloc(8192ull * 3072 * 2 + 64ull * 64 * 2048 * 2);
  unsigned short* qkv = (unsigned short*)regionE;           // live: QKV..attn
  unsigned short* vT = (unsigned short*)(regionE + 8192ull * 3072 * 2);
  unsigned short* act = (unsigned short*)regionE;           // live: FFN
  float* lbuf = (float*)alloc(64ull * 2048 * 4);
  float* x1 = (float*)alloc(8192ull * 1024 * 4);
  unsigned short* fbuf = (unsigned short*)alloc(8192ull * 1024 * 2);
  unsigned short* obuf = hbuf;  // h dead after QKV GEMM

  (void)in_sizes; (void)n_in; (void)out_size; (void)ws_size;

  // weight packing (B^T bf16 layouts)
  pack_qkv<<<dim3(16, 16, 3), 256, 0, stream>>>(Wq, Wk, Wv, Wqkv);
  transpose_cast<<<dim3(16, 16), 256, 0, stream>>>(Wo, WoT, 1024, 1024);
  transpose_cast<<<dim3(16, 64), 256, 0, stream>>>(W1, W1T, 1024, 4096);
  transpose_cast<<<dim3(64, 16), 256, 0, stream>>>(W2, W2T, 4096, 1024);
  // LN1 -> h
  ln_bf16<<<8192, 256, 0, stream>>>(x, g1, b1, hbuf);
  // QKV projection: [8192,1024]@[1024,3072]
  gemm_bt<0><<<dim3(24, 64), 256, 0, stream>>>(hbuf, Wqkv, 8192, 3072, 1024,
                                               qkv, nullptr, nullptr, nullptr);
  // V transpose for PV B-operand
  vtrans<<<dim3(32, 64), 256, 0, stream>>>(qkv, vT);
  // attention
  attn_stats<<<dim3(16, 64), 256, 0, stream>>>(qkv, lbuf);
  attn_pv<<<dim3(8, 64), 256, 0, stream>>>(qkv, vT, lbuf, obuf);
  // x1 = x + O@Wo + bo
  gemm_bt<1><<<dim3(8, 64), 256, 0, stream>>>(obuf, WoT, 8192, 1024, 1024,
                                              nullptr, x1, bo, x);
  // LN2 -> f
  ln_bf16<<<8192, 256, 0, stream>>>(x1, g2, b2, fbuf);
  // FFN1: relu(f@W1 + bf1) -> act bf16 [8192,4096]
  gemm_bt<2><<<dim3(32, 64), 256, 0, stream>>>(fbuf, W1T, 8192, 4096, 1024, act,
                                               nullptr, bf1, nullptr);
  // FFN2 + residual: out = x1 + act@W2 + bf2
  gemm_bt<1><<<dim3(8, 64), 256, 0, stream>>>(act, W2T, 8192, 1024, 4096,
                                              nullptr, out, bf2, x1);
}

// Round 4
// 435.778 us; speedup vs baseline: 2.0045x; 1.0824x over previous
//
#include <hip/hip_runtime.h>

// ---------------------------------------------------------------------------
// Transformer block fwd (B=4,T=2048,C=1024,H=16,HS=64,FF=4096), fp32 in/out,
// bf16 MFMA internally.  Column-softmax (axis=-2) via two-pass maxless exp2.
// R4: gemm256 = 8-wave 256x256 deep-pipelined GEMM (stage-early/wait-late,
//     T1 XCD swizzle, T2 granule-XOR LDS swizzle, T5 setprio) for QKV+FFN1;
//     linv folded into V (vtrans) so attn_pv needs no stats.
// ---------------------------------------------------------------------------

#define T_SEQ 2048
#define SCALE2 0.1803368801f  // 0.125 * log2(e): 2^(s*SCALE2) == e^(s/8)

typedef __attribute__((ext_vector_type(8))) short short8;  // 8 x bf16 (4 VGPR)
typedef __attribute__((ext_vector_type(4))) float f32x4;   // MFMA 16x16 acc

typedef __attribute__((address_space(1))) unsigned int g_u32;
typedef __attribute__((address_space(3))) unsigned int l_u32;

__device__ __forceinline__ unsigned short f2bf(float f) {
  union { float f; unsigned u; } x; x.f = f;
  unsigned r = (x.u + 0x7FFFu + ((x.u >> 16) & 1u)) >> 16;  // RNE
  return (unsigned short)r;
}
__device__ __forceinline__ float bf2f(unsigned short u) {
  union { unsigned u; float f; } x; x.u = (unsigned)u << 16;
  return x.f;
}

__device__ __forceinline__ void g2lds16(const void* g, void* l) {
  // async global->LDS, 16B/lane; LDS dest is wave-uniform base + lane*16
  __builtin_amdgcn_global_load_lds((g_u32*)g, (l_u32*)l, 16, 0, 0);
}

// bijective XCD swizzle for nwg % 8 == 0: XCD x gets a contiguous work chunk
__device__ __forceinline__ int xcd_swz(int flat, int nwg) {
  if ((nwg & 7) != 0) return flat;
  return (flat & 7) * (nwg >> 3) + (flat >> 3);
}

// ---------------------------------------------------------------------------
// gemm256: C[M,N] = A[M,K] @ Bt[N,K]^T, 256x256 tile, BK=64, 8 waves (2Mx4N),
// per-wave output 128x64 (acc[8][4]).  Double-buffered 128KB dynamic LDS.
// Pipeline: issue next K-tile's 8 global_load_lds at iteration top, compute
// 4 quadrant phases (4 ds_read + 16 MFMA each) on current buffer, single
// vmcnt-draining barrier per K-tile (loads age ~64 MFMA before the wait).
// EPI 0: bf16 = acc;  EPI 2: bf16 = relu(acc + bias[n])
// ---------------------------------------------------------------------------
template <int EPI>
__global__ __launch_bounds__(512, 2) void gemm256(
    const unsigned short* __restrict__ A, const unsigned short* __restrict__ Bt,
    int M, int N, int K,
    unsigned short* __restrict__ out16, const float* __restrict__ bias) {
  extern __shared__ unsigned short lds[];  // [2][16384] A, then [2][16384] B
  unsigned short* ldsA = lds;
  unsigned short* ldsB = lds + 2 * 16384;
  const int tid = threadIdx.x, lane = tid & 63, wid = tid >> 6;
  const int wm = wid >> 2, wn = wid & 3;
  const int nx = gridDim.x;
  const int flat = blockIdx.y * nx + blockIdx.x;
  const int swz = xcd_swz(flat, nx * gridDim.y);
  const int mBase = (swz / nx) * 256, nBase = (swz % nx) * 256;

  f32x4 acc[8][4];
#pragma unroll
  for (int i = 0; i < 8; ++i)
#pragma unroll
    for (int j = 0; j < 4; ++j)
#pragma unroll
      for (int e = 0; e < 4; ++e) acc[i][j][e] = 0.f;

  auto stage = [&](int buf, int kt) {
    const int k0 = kt << 6;
#pragma unroll
    for (int it = 0; it < 4; ++it) {
      int g = it * 512 + tid;            // granule 0..2047 (16B = 8 bf16)
      int row = g >> 3, colL = g & 7;
      int col = colL ^ (row & 7);        // inverse-swizzled source (rule #21)
      g2lds16(A + ((size_t)(mBase + row) * K + k0 + col * 8),
              &ldsA[buf * 16384 + (it * 512 + wid * 64) * 8]);
      g2lds16(Bt + ((size_t)(nBase + row) * K + k0 + col * 8),
              &ldsB[buf * 16384 + (it * 512 + wid * 64) * 8]);
    }
  };

  const int nKT = K >> 6;
  stage(0, 0);
  __syncthreads();  // prologue drain
  int cur = 0;
  for (int kt = 0; kt < nKT; ++kt) {
    if (kt + 1 < nKT) stage(cur ^ 1, kt + 1);  // issue early...

    short8 bf[4][2];  // B-frags once per K-tile (reused by all 4 phases)
#pragma unroll
    for (int fn = 0; fn < 4; ++fn)
#pragma unroll
      for (int ks = 0; ks < 2; ++ks) {
        int r = wn * 64 + fn * 16 + (lane & 15);
        int c = (ks * 4 + (lane >> 4)) ^ (r & 7);
        bf[fn][ks] = *(const short8*)&ldsB[cur * 16384 + r * 64 + c * 8];
      }
#pragma unroll
    for (int q = 0; q < 4; ++q) {  // 4 quadrant phases
      short8 af[2][2];
#pragma unroll
      for (int mf = 0; mf < 2; ++mf)
#pragma unroll
        for (int ks = 0; ks < 2; ++ks) {
          int r = wm * 128 + q * 32 + mf * 16 + (lane & 15);
          int c = (ks * 4 + (lane >> 4)) ^ (r & 7);
          af[mf][ks] = *(const short8*)&ldsA[cur * 16384 + r * 64 + c * 8];
        }
      __builtin_amdgcn_s_setprio(1);
#pragma unroll
      for (int mf = 0; mf < 2; ++mf)
#pragma unroll
        for (int fn = 0; fn < 4; ++fn)
#pragma unroll
          for (int ks = 0; ks < 2; ++ks)
            acc[q * 2 + mf][fn] = __builtin_amdgcn_mfma_f32_16x16x32_bf16(
                af[mf][ks], bf[fn][ks], acc[q * 2 + mf][fn], 0, 0, 0);
      __builtin_amdgcn_s_setprio(0);
    }
    __syncthreads();  // ...wait late: drains loads issued ~64 MFMA ago
    cur ^= 1;
  }

#pragma unroll
  for (int am = 0; am < 8; ++am)
#pragma unroll
    for (int fn = 0; fn < 4; ++fn) {
      int col = nBase + wn * 64 + fn * 16 + (lane & 15);
      int row0 = mBase + wm * 128 + am * 16 + ((lane >> 4) << 2);
      if (EPI == 0) {
#pragma unroll
        for (int r = 0; r < 4; ++r)
          out16[(size_t)(row0 + r) * N + col] = f2bf(acc[am][fn][r]);
      } else {
        float bv = bias[col];
#pragma unroll
        for (int r = 0; r < 4; ++r)
          out16[(size_t)(row0 + r) * N + col] =
              f2bf(fmaxf(acc[am][fn][r] + bv, 0.f));
      }
    }
}

// ---------------------------------------------------------------------------
// 128x128 GEMM (m97 structure) for the N=1024 GEMMs (grid 512 blocks).
// EPI 1: out f32 = acc + bias[n] + resid[m,n]
// ---------------------------------------------------------------------------
template <int EPI>
__global__ __launch_bounds__(256) void gemm_bt(
    const unsigned short* __restrict__ A, const unsigned short* __restrict__ Bt,
    int M, int N, int K,
    unsigned short* __restrict__ out16, float* __restrict__ outF,
    const float* __restrict__ bias, const float* __restrict__ resid) {
  __shared__ unsigned short ldsA[128 * 64];
  __shared__ unsigned short ldsB[128 * 64];
  const int tid = threadIdx.x;
  const int lane = tid & 63, wid = tid >> 6;
  const int wm = wid >> 1, wn = wid & 1;
  const int nx = gridDim.x;
  const int flat = blockIdx.y * nx + blockIdx.x;
  const int swz = xcd_swz(flat, nx * gridDim.y);
  const int mBase = (swz / nx) * 128, nBase = (swz % nx) * 128;

  f32x4 acc[4][4];
#pragma unroll
  for (int i = 0; i < 4; ++i)
#pragma unroll
    for (int j = 0; j < 4; ++j)
#pragma unroll
      for (int e = 0; e < 4; ++e) acc[i][j][e] = 0.f;

  const int nKT = K >> 6;
  for (int kt = 0; kt < nKT; ++kt) {
    const int k0 = kt << 6;
#pragma unroll
    for (int it = 0; it < 4; ++it) {
      int g = it * 256 + wid * 64 + lane;     // granule id 0..1023 (16B each)
      int row = g >> 3, colL = g & 7;
      int col = colL ^ (row & 7);             // inverse-swizzled source
      g2lds16(A + ((size_t)(mBase + row) * K + k0 + col * 8),
              &ldsA[(it * 256 + wid * 64) * 8]);
      g2lds16(Bt + ((size_t)(nBase + row) * K + k0 + col * 8),
              &ldsB[(it * 256 + wid * 64) * 8]);
    }
    __syncthreads();  // drains vmcnt -> tiles visible

    short8 af[4][2], bf[4][2];
#pragma unroll
    for (int fm = 0; fm < 4; ++fm)
#pragma unroll
      for (int ks = 0; ks < 2; ++ks) {
        int r = wm * 64 + fm * 16 + (lane & 15);
        int c = (ks * 4 + (lane >> 4)) ^ (r & 7);  // swizzled read
        af[fm][ks] = *(const short8*)&ldsA[r * 64 + c * 8];
      }
#pragma unroll
    for (int fn = 0; fn < 4; ++fn)
#pragma unroll
      for (int ks = 0; ks < 2; ++ks) {
        int r = wn * 64 + fn * 16 + (lane & 15);
        int c = (ks * 4 + (lane >> 4)) ^ (r & 7);
        bf[fn][ks] = *(const short8*)&ldsB[r * 64 + c * 8];
      }
    __builtin_amdgcn_s_setprio(1);
#pragma unroll
    for (int fm = 0; fm < 4; ++fm)
#pragma unroll
      for (int fn = 0; fn < 4; ++fn)
#pragma unroll
        for (int ks = 0; ks < 2; ++ks)
          acc[fm][fn] = __builtin_amdgcn_mfma_f32_16x16x32_bf16(
              af[fm][ks], bf[fn][ks], acc[fm][fn], 0, 0, 0);
    __builtin_amdgcn_s_setprio(0);
    __syncthreads();  // before next stage overwrites LDS
  }

#pragma unroll
  for (int fm = 0; fm < 4; ++fm)
#pragma unroll
    for (int fn = 0; fn < 4; ++fn) {
      int col = nBase + wn * 64 + fn * 16 + (lane & 15);
      int row0 = mBase + wm * 64 + fm * 16 + ((lane >> 4) << 2);
      if (EPI == 0) {
#pragma unroll
        for (int r = 0; r < 4; ++r)
          out16[(size_t)(row0 + r) * N + col] = f2bf(acc[fm][fn][r]);
      } else if (EPI == 1) {
        float bv = bias[col];
#pragma unroll
        for (int r = 0; r < 4; ++r) {
          size_t idx = (size_t)(row0 + r) * N + col;
          outF[idx] = acc[fm][fn][r] + bv + resid[idx];
        }
      } else {
        float bv = bias[col];
#pragma unroll
        for (int r = 0; r < 4; ++r)
          out16[(size_t)(row0 + r) * N + col] =
              f2bf(fmaxf(acc[fm][fn][r] + bv, 0.f));
      }
    }
}

// ---------------------------------------------------------------------------
// LayerNorm + bf16 cast.  One block per row of 1024.
// ---------------------------------------------------------------------------
__global__ __launch_bounds__(256) void ln_bf16(
    const float* __restrict__ x, const float* __restrict__ gw,
    const float* __restrict__ bw, unsigned short* __restrict__ out) {
  __shared__ float red[8];
  const int row = blockIdx.x, tid = threadIdx.x;
  const float4 v = ((const float4*)(x + (size_t)row * 1024))[tid];
  float s = v.x + v.y + v.z + v.w;
  float q = v.x * v.x + v.y * v.y + v.z * v.z + v.w * v.w;
#pragma unroll
  for (int off = 32; off >= 1; off >>= 1) {
    s += __shfl_down(s, off);
    q += __shfl_down(q, off);
  }
  const int lane = tid & 63, wid = tid >> 6;
  if (lane == 0) { red[wid] = s; red[4 + wid] = q; }
  __syncthreads();
  float S = red[0] + red[1] + red[2] + red[3];
  float Q = red[4] + red[5] + red[6] + red[7];
  float mu = S * (1.f / 1024.f);
  float var = Q * (1.f / 1024.f) - mu * mu;
  float rs = rsqrtf(var + 1e-5f);
  int c = tid * 4;
  ushort4 ov;
  ov.x = f2bf((v.x - mu) * rs * gw[c + 0] + bw[c + 0]);
  ov.y = f2bf((v.y - mu) * rs * gw[c + 1] + bw[c + 1]);
  ov.z = f2bf((v.z - mu) * rs * gw[c + 2] + bw[c + 2]);
  ov.w = f2bf((v.w - mu) * rs * gw[c + 3] + bw[c + 3]);
  *(ushort4*)&out[(size_t)row * 1024 + c] = ov;
}

// ---------------------------------------------------------------------------
// Weight packing: per-head Wq/Wk/Wv [H,C,HS] f32 -> Wqkv bf16 [3072][1024]
// ---------------------------------------------------------------------------
__global__ __launch_bounds__(256) void pack_qkv(
    const float* __restrict__ Wq, const float* __restrict__ Wk,
    const float* __restrict__ Wv, unsigned short* __restrict__ out) {
  __shared__ float tile[64 * 65];
  const int tid = threadIdx.x;
  const float* W = (blockIdx.z == 0) ? Wq : (blockIdx.z == 1) ? Wk : Wv;
  const int h = blockIdx.y, r0 = blockIdx.x * 64;
#pragma unroll
  for (int it = 0; it < 4; ++it) {
    int e4 = it * 256 + tid;
    int r = e4 >> 4, c4 = e4 & 15;
    float4 v = *(const float4*)&W[((size_t)h * 1024 + r0 + r) * 64 + c4 * 4];
    tile[r * 65 + c4 * 4 + 0] = v.x;
    tile[r * 65 + c4 * 4 + 1] = v.y;
    tile[r * 65 + c4 * 4 + 2] = v.z;
    tile[r * 65 + c4 * 4 + 3] = v.w;
  }
  __syncthreads();
#pragma unroll
  for (int it = 0; it < 4; ++it) {
    int e4 = it * 256 + tid;
    int d = e4 >> 4, r4 = e4 & 15;
    ushort4 ov;
    ov.x = f2bf(tile[(r4 * 4 + 0) * 65 + d]);
    ov.y = f2bf(tile[(r4 * 4 + 1) * 65 + d]);
    ov.z = f2bf(tile[(r4 * 4 + 2) * 65 + d]);
    ov.w = f2bf(tile[(r4 * 4 + 3) * 65 + d]);
    *(ushort4*)&out[(size_t)(blockIdx.z * 1024 + h * 64 + d) * 1024 + r0 +
                    r4 * 4] = ov;
  }
}

// Generic transpose+cast: in f32 [R,C] -> out bf16 [C,R].  grid (R/64, C/64).
__global__ __launch_bounds__(256) void transpose_cast(
    const float* __restrict__ in, unsigned short* __restrict__ out, int R,
    int C) {
  __shared__ float tile[64 * 65];
  const int tid = threadIdx.x;
  const int r0 = blockIdx.x * 64, c0 = blockIdx.y * 64;
#pragma unroll
  for (int it = 0; it < 4; ++it) {
    int e4 = it * 256 + tid;
    int r = e4 >> 4, c4 = e4 & 15;
    float4 v = *(const float4*)&in[(size_t)(r0 + r) * C + c0 + c4 * 4];
    tile[r * 65 + c4 * 4 + 0] = v.x;
    tile[r * 65 + c4 * 4 + 1] = v.y;
    tile[r * 65 + c4 * 4 + 2] = v.z;
    tile[r * 65 + c4 * 4 + 3] = v.w;
  }
  __syncthreads();
#pragma unroll
  for (int it = 0; it < 4; ++it) {
    int e4 = it * 256 + tid;
    int c = e4 >> 4, r4 = e4 & 15;
    ushort4 ov;
    ov.x = f2bf(tile[(r4 * 4 + 0) * 65 + c]);
    ov.y = f2bf(tile[(r4 * 4 + 1) * 65 + c]);
    ov.z = f2bf(tile[(r4 * 4 + 2) * 65 + c]);
    ov.w = f2bf(tile[(r4 * 4 + 3) * 65 + c]);
    *(ushort4*)&out[(size_t)(c0 + c) * R + r0 + r4 * 4] = ov;
  }
}

// V slice of qkv (cols 2048..3071) -> vT bf16 [B*H*64][T], PRE-SCALED by
// linv[s]:  vT[d][t] = V[t][d] * linv[t]   (folds softmax denom into V).
__global__ __launch_bounds__(256) void vtrans(
    const unsigned short* __restrict__ qkv, const float* __restrict__ linv,
    unsigned short* __restrict__ vT) {
  __shared__ unsigned short tile[64 * 66];
  const int tid = threadIdx.x;
  const int bh = blockIdx.y, b = bh >> 4, h = bh & 15;
  const int t0 = blockIdx.x * 64;
#pragma unroll
  for (int it = 0; it < 8; ++it) {
    int e2 = it * 256 + tid;
    int r = e2 >> 5, c2 = e2 & 31;
    unsigned v = *(const unsigned*)&qkv[(size_t)(b * T_SEQ + t0 + r) * 3072 +
                                        2048 + h * 64 + c2 * 2];
    float li = linv[(size_t)bh * T_SEQ + t0 + r];
    unsigned short lo = f2bf(bf2f((unsigned short)(v & 0xffff)) * li);
    unsigned short hi = f2bf(bf2f((unsigned short)(v >> 16)) * li);
    *(unsigned*)&tile[r * 66 + c2 * 2] = (unsigned)lo | ((unsigned)hi << 16);
  }
  __syncthreads();
#pragma unroll
  for (int it = 0; it < 8; ++it) {
    int e2 = it * 256 + tid;
    int d = e2 >> 5, t2 = e2 & 31;
    unsigned short a = tile[(t2 * 2) * 66 + d];
    unsigned short bb = tile[(t2 * 2 + 1) * 66 + d];
    unsigned pk = (unsigned)a | ((unsigned)bb << 16);
    *(unsigned*)&vT[(size_t)(bh * 64 + d) * T_SEQ + t0 + t2 * 2] = pk;
  }
}

// ---------------------------------------------------------------------------
// Attention pass A: l[s] = sum_{t>=s} 2^(S[t,s]*SCALE2)  -- maxless.
// ---------------------------------------------------------------------------
__global__ __launch_bounds__(256) void attn_stats(
    const unsigned short* __restrict__ qkv, float* __restrict__ linvOut) {
  __shared__ unsigned short qt[4][2][64 * 64];  // per-wave double buffer
  __shared__ float redL[4][2][64];
  const int tid = threadIdx.x, lane = tid & 63, w = tid >> 6;
  const int bh = blockIdx.y, b = bh >> 4, h = bh & 15;
  const int sx = blockIdx.x;
  const int sA = sx * 64, sB = (31 - sx) * 64;
  const int nT = 32 - sx;          // t-tiles from sA to end (>= 17)
  const int bDiag = 31 - 2 * sx;   // idx where t0 == sB

  short8 kfA[4][2], kfB[4][2];
#pragma unroll
  for (int fn = 0; fn < 4; ++fn)
#pragma unroll
    for (int ks = 0; ks < 2; ++ks) {
      int d = 1024 + h * 64 + ks * 32 + ((lane >> 4) << 3);
      kfA[fn][ks] = *(const short8*)&qkv[(size_t)(b * T_SEQ + sA + fn * 16 +
                                                  (lane & 15)) * 3072 + d];
      kfB[fn][ks] = *(const short8*)&qkv[(size_t)(b * T_SEQ + sB + fn * 16 +
                                                  (lane & 15)) * 3072 + d];
    }
  float lA[4] = {0.f, 0.f, 0.f, 0.f}, lB[4] = {0.f, 0.f, 0.f, 0.f};

  auto stageQ = [&](int buf, int idx) {
    int t0 = sA + idx * 64;
#pragma unroll
    for (int it = 0; it < 8; ++it) {
      int g = it * 64 + lane;
      int row = g >> 3;
      int col = (g & 7) ^ (row & 7);  // inverse-swizzled source
      g2lds16(qkv + ((size_t)(b * T_SEQ + t0 + row) * 3072 + h * 64 + col * 8),
              &qt[w][buf][it * 512]);
    }
  };

  auto accum = [&](const short8 (&af)[2], const short8 (&kf)[4][2],
                   float (&lacc)[4], int sBase, int t0, int mf, bool diag) {
    f32x4 sc[4];
#pragma unroll
    for (int fn = 0; fn < 4; ++fn)
#pragma unroll
      for (int e = 0; e < 4; ++e) sc[fn][e] = 0.f;
    __builtin_amdgcn_s_setprio(1);
#pragma unroll
    for (int fn = 0; fn < 4; ++fn)
#pragma unroll
      for (int ks = 0; ks < 2; ++ks)
        sc[fn] = __builtin_amdgcn_mfma_f32_16x16x32_bf16(af[ks], kf[fn][ks],
                                                         sc[fn], 0, 0, 0);
    __builtin_amdgcn_s_setprio(0);
    const int tRow = t0 + mf * 16 + ((lane >> 4) << 2);
    if (diag) {
#pragma unroll
      for (int fn = 0; fn < 4; ++fn) {
        int s = sBase + fn * 16 + (lane & 15);
#pragma unroll
        for (int r = 0; r < 4; ++r) {
          float e = exp2f(sc[fn][r] * SCALE2);
          lacc[fn] += (tRow + r >= s) ? e : 0.f;
        }
      }
    } else {
#pragma unroll
      for (int fn = 0; fn < 4; ++fn)
#pragma unroll
        for (int r = 0; r < 4; ++r) lacc[fn] += exp2f(sc[fn][r] * SCALE2);
    }
  };

  int idx = w, cur = 0;
  stageQ(0, idx);  // nT >= 17 so every wave has work
  for (; idx < nT; idx += 4, cur ^= 1) {
    if (idx + 4 < nT) {
      stageQ(cur ^ 1, idx + 4);
      asm volatile("s_waitcnt vmcnt(8)" ::: "memory");  // cur buf resident
    } else {
      asm volatile("s_waitcnt vmcnt(0)" ::: "memory");
    }
    const int t0 = sA + idx * 64;
    const bool doB = idx >= bDiag;
#pragma unroll
    for (int mf = 0; mf < 4; ++mf) {
      short8 af[2];
#pragma unroll
      for (int ks = 0; ks < 2; ++ks) {
        int r = mf * 16 + (lane & 15);
        int c = (ks * 4 + (lane >> 4)) ^ (r & 7);
        af[ks] = *(const short8*)&qt[w][cur][r * 64 + c * 8];
      }
      accum(af, kfA, lA, sA, t0, mf, idx == 0);
      if (doB) accum(af, kfB, lB, sB, t0, mf, idx == bDiag);
    }
  }
#pragma unroll
  for (int fn = 0; fn < 4; ++fn) {
    lA[fn] += __shfl_down(lA[fn], 32);
    lA[fn] += __shfl_down(lA[fn], 16);
    lB[fn] += __shfl_down(lB[fn], 32);
    lB[fn] += __shfl_down(lB[fn], 16);
  }
  if (lane < 16) {
#pragma unroll
    for (int fn = 0; fn < 4; ++fn) {
      redL[w][0][fn * 16 + lane] = lA[fn];
      redL[w][1][fn * 16 + lane] = lB[fn];
    }
  }
  __syncthreads();
  if (tid < 128) {
    int which = tid >> 6;  // 0 -> A, 1 -> B
    float l = redL[0][which][lane] + redL[1][which][lane] +
              redL[2][which][lane] + redL[3][which][lane];
    int sbase = (which == 0) ? sA : sB;
    linvOut[(size_t)bh * T_SEQ + sbase + lane] = 1.f / l;
  }
}

// ---------------------------------------------------------------------------
// Attention pass B: O[t,:] = sum_s 2^(S[t,s]*SCALE2) * vT_scaled[:,s]
// (linv pre-folded into vT).  Row-tile PAIR per block for load balance.
// ---------------------------------------------------------------------------
__global__ __launch_bounds__(256, 2) void attn_pv(
    const unsigned short* __restrict__ qkv, const unsigned short* __restrict__ vT,
    unsigned short* __restrict__ o) {
  __shared__ unsigned short kbuf[2][64 * 64];
  __shared__ unsigned short vbuf[2][64 * 64];
  __shared__ unsigned short pl[256 * 64];  // rows 0-127: A, 128-255: B
  const int tid = threadIdx.x, lane = tid & 63, wid = tid >> 6;
  const int bh = blockIdx.y, b = bh >> 4, h = bh & 15;
  const int bx = blockIdx.x;
  const int tA = bx * 128, tB = (15 - bx) * 128;
  const int nSTA = 2 * bx + 2, nSTB = 32 - 2 * bx;  // nSTA < nSTB always

  short8 qfA[2][2], qfB[2][2];
#pragma unroll
  for (int mf = 0; mf < 2; ++mf)
#pragma unroll
    for (int ks = 0; ks < 2; ++ks) {
      int d = h * 64 + ks * 32 + ((lane >> 4) << 3);
      int rloc = wid * 32 + mf * 16 + (lane & 15);
      qfA[mf][ks] =
          *(const short8*)&qkv[(size_t)(b * T_SEQ + tA + rloc) * 3072 + d];
      qfB[mf][ks] =
          *(const short8*)&qkv[(size_t)(b * T_SEQ + tB + rloc) * 3072 + d];
    }
  f32x4 oaccA[2][4], oaccB[2][4];
#pragma unroll
  for (int i = 0; i < 2; ++i)
#pragma unroll
    for (int j = 0; j < 4; ++j)
#pragma unroll
      for (int e = 0; e < 4; ++e) { oaccA[i][j][e] = 0.f; oaccB[i][j][e] = 0.f; }

  auto stage = [&](int buf, int st) {
#pragma unroll
    for (int it = 0; it < 2; ++it) {
      int g = it * 256 + tid;            // granule 0..511 (16B each)
      int row = g >> 3, colL = g & 7;
      int col = colL ^ (row & 7);        // inverse-swizzled source
      g2lds16(qkv + ((size_t)(b * T_SEQ + st * 64 + row) * 3072 + 1024 +
                     h * 64 + col * 8),
              &kbuf[buf][(it * 256 + wid * 64) * 8]);
      g2lds16(vT + ((size_t)(bh * 64 + row) * T_SEQ + st * 64 + col * 8),
              &vbuf[buf][(it * 256 + wid * 64) * 8]);
    }
  };

  // QK^T for one row-tile from LDS K-tile, exp2, store P into pl
  auto qkstore = [&](const short8 (&qf)[2][2], int rowBase, int tBase, int s0,
                     bool maskNeeded, int cur) {
    f32x4 sc[2][4];
#pragma unroll
    for (int i = 0; i < 2; ++i)
#pragma unroll
      for (int j = 0; j < 4; ++j)
#pragma unroll
        for (int e = 0; e < 4; ++e) sc[i][j][e] = 0.f;
    __builtin_amdgcn_s_setprio(1);
#pragma unroll
    for (int fn = 0; fn < 4; ++fn)
#pragma unroll
      for (int ks = 0; ks < 2; ++ks) {
        int r = fn * 16 + (lane & 15);
        int c = (ks * 4 + (lane >> 4)) ^ (r & 7);
        short8 kfr = *(const short8*)&kbuf[cur][r * 64 + c * 8];
        sc[0][fn] = __builtin_amdgcn_mfma_f32_16x16x32_bf16(qf[0][ks], kfr,
                                                            sc[0][fn], 0, 0, 0);
        sc[1][fn] = __builtin_amdgcn_mfma_f32_16x16x32_bf16(qf[1][ks], kfr,
                                                            sc[1][fn], 0, 0, 0);
      }
    __builtin_amdgcn_s_setprio(0);
#pragma unroll
    for (int fn = 0; fn < 4; ++fn) {
      int sg = s0 + fn * 16 + (lane & 15);
      int colb = (fn * 16 + (lane & 15)) * 2;
#pragma unroll
      for (int mf = 0; mf < 2; ++mf) {
        int rowB = rowBase + wid * 32 + mf * 16 + ((lane >> 4) << 2);
        int tRow = tBase + wid * 32 + mf * 16 + ((lane >> 4) << 2);
#pragma unroll
        for (int r = 0; r < 4; ++r) {
          float p = exp2f(sc[mf][fn][r] * SCALE2);
          if (maskNeeded) p = (tRow + r >= sg) ? p : 0.f;
          int row = rowB + r;
          int byteoff = row * 128 + (colb ^ ((row & 7) << 4));
          *(unsigned short*)((char*)pl + byteoff) = f2bf(p);
        }
      }
    }
  };

  stage(0, 0);
  int cur = 0;
  __syncthreads();  // tile 0 resident

  for (int st = 0; st < nSTB; ++st) {
    const int s0 = st * 64;
    const bool doA = st < nSTA;

    if (doA) qkstore(qfA, 0, tA, s0, st >= nSTA - 2, cur);
    qkstore(qfB, 128, tB, s0, st >= nSTB - 2, cur);
    __syncthreads();  // pl ready

    if (st + 1 < nSTB) stage(cur ^ 1, st + 1);  // overlaps PV

    __builtin_amdgcn_s_setprio(1);
#pragma unroll
    for (int ks = 0; ks < 2; ++ks) {
      short8 paA[2], paB[2];
#pragma unroll
      for (int mf = 0; mf < 2; ++mf) {
        int rowa = wid * 32 + mf * 16 + (lane & 15);
        int kb = ks * 64 + ((lane >> 4) << 4);
        paB[mf] = *(const short8*)((const char*)pl + (128 + rowa) * 128 +
                                   (kb ^ ((rowa & 7) << 4)));
        if (doA)
          paA[mf] = *(const short8*)((const char*)pl + rowa * 128 +
                                     (kb ^ ((rowa & 7) << 4)));
      }
#pragma unroll
      for (int df = 0; df < 4; ++df) {
        int r = df * 16 + (lane & 15);
        int c = (ks * 4 + (lane >> 4)) ^ (r & 7);
        short8 vb = *(const short8*)&vbuf[cur][r * 64 + c * 8];
        oaccB[0][df] = __builtin_amdgcn_mfma_f32_16x16x32_bf16(paB[0], vb,
                                                               oaccB[0][df], 0, 0, 0);
        oaccB[1][df] = __builtin_amdgcn_mfma_f32_16x16x32_bf16(paB[1], vb,
                                                               oaccB[1][df], 0, 0, 0);
        if (doA) {
          oaccA[0][df] = __builtin_amdgcn_mfma_f32_16x16x32_bf16(paA[0], vb,
                                                                 oaccA[0][df], 0, 0, 0);
          oaccA[1][df] = __builtin_amdgcn_mfma_f32_16x16x32_bf16(paA[1], vb,
                                                                 oaccA[1][df], 0, 0, 0);
        }
      }
    }
    __builtin_amdgcn_s_setprio(0);
    __syncthreads();  // drains prefetch; pl free
    cur ^= 1;
  }
  // write O as bf16 [B,T,C] (c = h*64+d)
#pragma unroll
  for (int mf = 0; mf < 2; ++mf)
#pragma unroll
    for (int df = 0; df < 4; ++df) {
      int d = h * 64 + df * 16 + (lane & 15);
      int ra = tA + wid * 32 + mf * 16 + ((lane >> 4) << 2);
      int rb = tB + wid * 32 + mf * 16 + ((lane >> 4) << 2);
#pragma unroll
      for (int r = 0; r < 4; ++r) {
        o[(size_t)(b * T_SEQ + ra + r) * 1024 + d] = f2bf(oaccA[mf][df][r]);
        o[(size_t)(b * T_SEQ + rb + r) * 1024 + d] = f2bf(oaccB[mf][df][r]);
      }
    }
}

// ---------------------------------------------------------------------------
extern "C" void kernel_launch(void* const* d_in, const int* in_sizes, int n_in,
                              void* d_out, int out_size, void* d_ws,
                              size_t ws_size, hipStream_t stream) {
  const float* x = (const float*)d_in[0];
  const float* Wq = (const float*)d_in[1];
  const float* Wk = (const float*)d_in[2];
  const float* Wv = (const float*)d_in[3];
  const float* Wo = (const float*)d_in[4];
  const float* bo = (const float*)d_in[5];
  const float* g1 = (const float*)d_in[6];
  const float* b1 = (const float*)d_in[7];
  const float* g2 = (const float*)d_in[8];
  const float* b2 = (const float*)d_in[9];
  const float* W1 = (const float*)d_in[10];
  const float* bf1 = (const float*)d_in[11];
  const float* W2 = (const float*)d_in[12];
  const float* bf2 = (const float*)d_in[13];
  float* out = (float*)d_out;

  char* ws = (char*)d_ws;
  size_t off = 0;
  auto alloc = [&](size_t bytes) {
    char* p = ws + off;
    off += (bytes + 255) & ~(size_t)255;
    return p;
  };
  unsigned short* Wqkv = (unsigned short*)alloc(3072ull * 1024 * 2);
  unsigned short* WoT = (unsigned short*)alloc(1024ull * 1024 * 2);
  unsigned short* W1T = (unsigned short*)alloc(4096ull * 1024 * 2);
  unsigned short* W2T = (unsigned short*)alloc(1024ull * 4096 * 2);
  unsigned short* hbuf = (unsigned short*)alloc(8192ull * 1024 * 2);  // h, then o
  char* regionE = alloc(8192ull * 3072 * 2 + 64ull * 64 * 2048 * 2);
  unsigned short* qkv = (unsigned short*)regionE;           // live: QKV..attn
  unsigned short* vT = (unsigned short*)(regionE + 8192ull * 3072 * 2);
  unsigned short* act = (unsigned short*)regionE;           // live: FFN
  float* lbuf = (float*)alloc(64ull * 2048 * 4);
  float* x1 = (float*)alloc(8192ull * 1024 * 4);
  unsigned short* fbuf = (unsigned short*)alloc(8192ull * 1024 * 2);
  unsigned short* obuf = hbuf;  // h dead after QKV GEMM

  (void)in_sizes; (void)n_in; (void)out_size; (void)ws_size;

  // weight packing (B^T bf16 layouts)
  pack_qkv<<<dim3(16, 16, 3), 256, 0, stream>>>(Wq, Wk, Wv, Wqkv);
  transpose_cast<<<dim3(16, 16), 256, 0, stream>>>(Wo, WoT, 1024, 1024);
  transpose_cast<<<dim3(16, 64), 256, 0, stream>>>(W1, W1T, 1024, 4096);
  transpose_cast<<<dim3(64, 16), 256, 0, stream>>>(W2, W2T, 4096, 1024);
  // LN1 -> h
  ln_bf16<<<8192, 256, 0, stream>>>(x, g1, b1, hbuf);
  // QKV projection: [8192,1024]@[1024,3072]  (256x256 pipelined GEMM)
  gemm256<0><<<dim3(12, 32), 512, 131072, stream>>>(hbuf, Wqkv, 8192, 3072,
                                                    1024, qkv, nullptr);
  // attention stats (needs only Q,K slices of qkv)
  attn_stats<<<dim3(16, 64), 256, 0, stream>>>(qkv, lbuf);
  // V transpose, pre-scaled by linv
  vtrans<<<dim3(32, 64), 256, 0, stream>>>(qkv, lbuf, vT);
  // attention PV
  attn_pv<<<dim3(8, 64), 256, 0, stream>>>(qkv, vT, obuf);
  // x1 = x + O@Wo + bo
  gemm_bt<1><<<dim3(8, 64), 256, 0, stream>>>(obuf, WoT, 8192, 1024, 1024,
                                              nullptr, x1, bo, x);
  // LN2 -> f
  ln_bf16<<<8192, 256, 0, stream>>>(x1, g2, b2, fbuf);
  // FFN1: relu(f@W1 + bf1) -> act bf16 [8192,4096]  (256x256 pipelined GEMM)
  gemm256<2><<<dim3(16, 32), 512, 131072, stream>>>(fbuf, W1T, 8192, 4096,
                                                    1024, act, bf1);
  // FFN2 + residual: out = x1 + act@W2 + bf2
  gemm_bt<1><<<dim3(8, 64), 256, 0, stream>>>(act, W2T, 8192, 1024, 4096,
                                              nullptr, out, bf2, x1);
}